// Round 17
// baseline (129.778 us; speedup 1.0000x reference)
//
#include <hip/hip_runtime.h>

#define T_SEQ 1024
#define DH 64
#define NH 8
#define NB 2
#define EMB 512
#define CS 64      // tokens per scan chunk
#define NCH 16     // chunks per chain
#define ACH 16     // attention chunks per chain (64 tokens each)
#define NCHAIN 16  // B*H

typedef __attribute__((ext_vector_type(8))) short bf16x8;
typedef __attribute__((ext_vector_type(4))) float f32x4;

__device__ __forceinline__ int swz4(int r, int c4) {
    return r * 16 + ((c4 ^ (r >> 2)) & 15);
}

__device__ __forceinline__ void fma4(float4& o, float s, const float4& b) {
    o.x += s * b.x; o.y += s * b.y; o.z += s * b.z; o.w += s * b.w;
}

__device__ __forceinline__ ushort f2bf(float f) {
    unsigned u = __float_as_uint(f);
    return (ushort)((u + 0x7FFFu + ((u >> 16) & 1u)) >> 16);
}
__device__ __forceinline__ float bf2f(ushort h) {
    return __uint_as_float(((unsigned)h) << 16);
}
__device__ __forceinline__ void split2(float f, ushort& hi, ushort& lo) {
    hi = f2bf(f);
    lo = f2bf(f - bf2f(hi));
}

// ---------------------------------------------------------------------------
// prep_qkv: z<3 -> transpose+split W{q,k,v}; z==3 -> split x.
// ---------------------------------------------------------------------------
__global__ __launch_bounds__(256) void prep_qkv(
    const float* __restrict__ x, const float* __restrict__ W0,
    const float* __restrict__ W1, const float* __restrict__ W2,
    ushort* __restrict__ x_hi, ushort* __restrict__ x_lo,
    ushort* __restrict__ Wt_hi, ushort* __restrict__ Wt_lo) {
    int zz = blockIdx.z;
    int t = threadIdx.x;
    __shared__ float T[64][65];
    if (zz < 3) {
        const float* W = (zz == 0) ? W0 : (zz == 1) ? W1 : W2;
        ushort* hi = Wt_hi + (size_t)zz * 262144;
        ushort* lo = Wt_lo + (size_t)zz * 262144;
        int kk0 = blockIdx.x * 64, n0 = blockIdx.y * 64;
#pragma unroll
        for (int i = 0; i < 4; ++i) {
            int rl = i * 16 + (t >> 4);
            float4 vv = *(const float4*)&W[(size_t)(kk0 + rl) * 512 + n0 + (t & 15) * 4];
            T[rl][(t & 15) * 4 + 0] = vv.x;
            T[rl][(t & 15) * 4 + 1] = vv.y;
            T[rl][(t & 15) * 4 + 2] = vv.z;
            T[rl][(t & 15) * 4 + 3] = vv.w;
        }
        __syncthreads();
        int nl = t >> 2, kl = (t & 3) * 16;
#pragma unroll
        for (int j4 = 0; j4 < 4; ++j4) {
            ushort4 h4, l4;
            split2(T[kl + j4 * 4 + 0][nl], h4.x, l4.x);
            split2(T[kl + j4 * 4 + 1][nl], h4.y, l4.y);
            split2(T[kl + j4 * 4 + 2][nl], h4.z, l4.z);
            split2(T[kl + j4 * 4 + 3][nl], h4.w, l4.w);
            size_t dst = (size_t)(n0 + nl) * 512 + kk0 + kl + j4 * 4;
            *(ushort4*)&hi[dst] = h4;
            *(ushort4*)&lo[dst] = l4;
        }
    } else {
        int bid = blockIdx.y * 8 + blockIdx.x;
        const float4* in = (const float4*)x;
        ushort4* hi = (ushort4*)x_hi;
        ushort4* lo = (ushort4*)x_lo;
#pragma unroll
        for (int i = 0; i < 16; ++i) {
            int id = (bid * 16 + i) * 256 + t;
            float4 xv = in[id];
            ushort4 h, l;
            split2(xv.x, h.x, l.x);
            split2(xv.y, h.y, l.y);
            split2(xv.z, h.z, l.z);
            split2(xv.w, h.w, l.w);
            hi[id] = h;
            lo[id] = l;
        }
    }
}

// ---------------------------------------------------------------------------
// MFMA GEMM: C[2048][512] = A * B, bf16 hi/lo split, Bt[n][k] transposed.
// ---------------------------------------------------------------------------
template <int MODE>
__global__ __launch_bounds__(256) void mfma_gemm(
    const ushort* __restrict__ Ahi, const ushort* __restrict__ Alo,
    const ushort* __restrict__ Bth, const ushort* __restrict__ Btl,
    float* __restrict__ o0, float* __restrict__ o1, float* __restrict__ o2) {
    int bm = blockIdx.x, bn = blockIdx.y, zz = blockIdx.z;
    const ushort* Bh = Bth + (size_t)zz * 262144;
    const ushort* Bl = Btl + (size_t)zz * 262144;
    float* out = (MODE == 0) ? ((zz == 0) ? o0 : (zz == 1) ? o1 : o2) : o0;

    __shared__ ushort Ash[128 * 40];
    __shared__ ushort Asl[128 * 40];
    __shared__ ushort Bsh[64 * 40];
    __shared__ ushort Bsl[64 * 40];

    int tid = threadIdx.x;
    int lane = tid & 63, wid = tid >> 6;
    int wm = wid >> 1, wn = wid & 1;
    int fr = lane & 15, fk = (lane >> 4) * 8;
    int sr = tid >> 2, sc = (tid & 3) * 8;

    f32x4 zero = {0.f, 0.f, 0.f, 0.f};
    f32x4 acc[4][2];
#pragma unroll
    for (int f = 0; f < 4; ++f)
#pragma unroll
        for (int g = 0; g < 2; ++g) acc[f][g] = zero;

    const ushort* gAh = Ahi + (size_t)(bm * 128 + sr) * 512 + sc;
    const ushort* gAl = Alo + (size_t)(bm * 128 + sr) * 512 + sc;
    const ushort* gBh = Bh + (size_t)(bn * 64 + sr) * 512 + sc;
    const ushort* gBl = Bl + (size_t)(bn * 64 + sr) * 512 + sc;

    for (int k0 = 0; k0 < 512; k0 += 32) {
        uint4 a0 = *(const uint4*)(gAh + k0);
        uint4 a1 = *(const uint4*)(gAh + 64 * 512 + k0);
        uint4 a2 = *(const uint4*)(gAl + k0);
        uint4 a3 = *(const uint4*)(gAl + 64 * 512 + k0);
        uint4 b0 = *(const uint4*)(gBh + k0);
        uint4 b1 = *(const uint4*)(gBl + k0);
        __syncthreads();
        *(uint4*)&Ash[sr * 40 + sc] = a0;
        *(uint4*)&Ash[(sr + 64) * 40 + sc] = a1;
        *(uint4*)&Asl[sr * 40 + sc] = a2;
        *(uint4*)&Asl[(sr + 64) * 40 + sc] = a3;
        *(uint4*)&Bsh[sr * 40 + sc] = b0;
        *(uint4*)&Bsl[sr * 40 + sc] = b1;
        __syncthreads();
        bf16x8 ah[4], al[4], bh[2], blo[2];
#pragma unroll
        for (int f = 0; f < 4; ++f) {
            int r = wm * 64 + f * 16 + fr;
            ah[f] = *(const bf16x8*)&Ash[r * 40 + fk];
            al[f] = *(const bf16x8*)&Asl[r * 40 + fk];
        }
#pragma unroll
        for (int g = 0; g < 2; ++g) {
            int r = wn * 32 + g * 16 + fr;
            bh[g] = *(const bf16x8*)&Bsh[r * 40 + fk];
            blo[g] = *(const bf16x8*)&Bsl[r * 40 + fk];
        }
#pragma unroll
        for (int f = 0; f < 4; ++f)
#pragma unroll
            for (int g = 0; g < 2; ++g) {
                acc[f][g] = __builtin_amdgcn_mfma_f32_16x16x32_bf16(
                    ah[f], bh[g], acc[f][g], 0, 0, 0);
                acc[f][g] = __builtin_amdgcn_mfma_f32_16x16x32_bf16(
                    ah[f], blo[g], acc[f][g], 0, 0, 0);
                acc[f][g] = __builtin_amdgcn_mfma_f32_16x16x32_bf16(
                    al[f], bh[g], acc[f][g], 0, 0, 0);
            }
    }

    int rbase = (lane >> 4) * 4;
#pragma unroll
    for (int f = 0; f < 4; ++f)
#pragma unroll
        for (int g = 0; g < 2; ++g)
#pragma unroll
            for (int j = 0; j < 4; ++j) {
                int m = bm * 128 + wm * 64 + f * 16 + rbase + j;
                int n = bn * 64 + wn * 32 + g * 16 + (lane & 15);
                float val = acc[f][g][j];
                if (MODE == 0) {
                    int b = m >> 10, tt = m & 1023;
                    int h = n >> 6, d = n & 63;
                    out[(((size_t)(b * 8 + h) * 1024 + tt) << 6) + d] = val;
                } else {
                    out[(size_t)m * 512 + n] = val;
                }
            }
}

// ---------------------------------------------------------------------------
// per-chunk Gram G = X^T X (64x64, CS=64 tokens)
// ---------------------------------------------------------------------------
__global__ __launch_bounds__(256) void gram_kernel(
    const float* __restrict__ v, float* __restrict__ g) {
    int chain = blockIdx.x, chunk = blockIdx.y;
    const float* X = v + ((size_t)chain * T_SEQ + chunk * CS) * DH;
    __shared__ float Xs[CS * 64];
    int tid = threadIdx.x;
#pragma unroll
    for (int i = 0; i < (CS * 16) / 256; ++i)
        ((float4*)Xs)[i * 256 + tid] = ((const float4*)X)[i * 256 + tid];
    __syncthreads();

    int tx = tid & 15, ty = tid >> 4;
    float acc[4][4];
#pragma unroll
    for (int i = 0; i < 4; ++i)
#pragma unroll
        for (int j = 0; j < 4; ++j) acc[i][j] = 0.f;

#pragma unroll 4
    for (int t = 0; t < CS; ++t) {
        float a_[4], b_[4];
#pragma unroll
        for (int i = 0; i < 4; ++i) a_[i] = Xs[t * 64 + ty * 4 + i];
#pragma unroll
        for (int j = 0; j < 4; ++j) b_[j] = Xs[t * 64 + tx * 4 + j];
#pragma unroll
        for (int i = 0; i < 4; ++i)
#pragma unroll
            for (int j = 0; j < 4; ++j) acc[i][j] += a_[i] * b_[j];
    }

    float* gp = g + ((size_t)chain * NCH + chunk) * 4096;
#pragma unroll
    for (int i = 0; i < 4; ++i)
        *(float4*)(gp + (ty * 4 + i) * 64 + tx * 4) =
            make_float4(acc[i][0], acc[i][1], acc[i][2], acc[i][3]);
}

// ---------------------------------------------------------------------------
// exclusive prefix over NCH chunks — register-staged
// ---------------------------------------------------------------------------
__global__ __launch_bounds__(256) void prefix_kernel(float* __restrict__ g) {
    int gid = blockIdx.x * 256 + threadIdx.x;   // 16 chains * 4096 elems
    int chain = gid >> 12, elem = gid & 4095;
    float* p = g + (size_t)chain * NCH * 4096 + elem;
    float vals[NCH];
#pragma unroll
    for (int c = 0; c < NCH; ++c) vals[c] = p[(size_t)c * 4096];
    float run = 0.f;
#pragma unroll
    for (int c = 0; c < NCH; ++c) {
        float t = vals[c];
        vals[c] = run;
        run += t;
    }
#pragma unroll
    for (int c = 0; c < NCH; ++c) p[(size_t)c * 4096] = vals[c];
}

// ---------------------------------------------------------------------------
// invscan_kv: heterogeneous grid. Blocks < nInv: RANK-4 GJ sweep (16 rounds)
// + rank-2 SM scan over CS=64 tokens (32 rounds). Blocks >= nInv: kv_gram.
// LDS union ~51KB.
// ---------------------------------------------------------------------------
__global__ __launch_bounds__(256) void invscan_kv(
    int nInv,
    const float* __restrict__ g, const float* __restrict__ v,
    const float* __restrict__ q, const float* __restrict__ lambdas,
    float* __restrict__ preds,
    const float* __restrict__ Kv, float* __restrict__ D) {
    __shared__ float smem[12848];
    int bid = blockIdx.x;
    int tid = threadIdx.x;

    if (bid < nInv) {
        int chain = bid >> 4, chunk = bid & 15;
        int row = tid >> 2, ch = tid & 3, wav = tid >> 6;
        float lam = lambdas[chain & (NH - 1)];

        float* Xs = smem;                 // 4096
        float* Qs = smem + 4096;          // 4096
        float* Po = smem + 8192;          // 4096
        float* Rq = smem + 12288;         // [2][4][64] = 512
        float* red = smem + 12800;        // [2][6][4] = 48

        float m[16];
        {
            const float4* gp = (const float4*)(g + ((size_t)chain * NCH + chunk) * 4096);
#pragma unroll
            for (int i = 0; i < 4; ++i) {
                float4 t4 = gp[row * 16 + ch * 4 + i];
                m[i * 4 + 0] = t4.x; m[i * 4 + 1] = t4.y;
                m[i * 4 + 2] = t4.z; m[i * 4 + 3] = t4.w;
            }
        }
#pragma unroll
        for (int i = 0; i < 16; ++i)
            if (ch * 16 + i == row) m[i] += lam;

        const float4* vb = (const float4*)(v + ((size_t)chain * T_SEQ + chunk * CS) * DH);
        const float4* qb = (const float4*)(q + ((size_t)chain * T_SEQ + chunk * CS) * DH);
#pragma unroll
        for (int j = 0; j < 4; ++j) {
            ((float4*)Xs)[j * 256 + tid] = vb[j * 256 + tid];
            ((float4*)Qs)[j * 256 + tid] = qb[j * 256 + tid];
        }

        if (row < 4) {
#pragma unroll
            for (int i = 0; i < 4; ++i)
                ((float4*)(Rq + row * 64))[ch * 4 + i] =
                    make_float4(m[i * 4], m[i * 4 + 1], m[i * 4 + 2], m[i * 4 + 3]);
        }
        __syncthreads();

        // ---- RANK-4 GJ sweep: pivots (p..p+3), 16 rounds ----
#pragma unroll
        for (int pp = 0; pp < 16; ++pp) {
            const int p = 4 * pp;
            const float* rb = Rq + (pp & 1) * 256;
            const float* sb = rb + 64;
            const float* tb = rb + 128;
            const float* ub = rb + 192;
            float r_[16], s_[16], t_[16], u_[16];
#pragma unroll
            for (int i = 0; i < 4; ++i) {
                float4 a4 = ((const float4*)rb)[ch * 4 + i];
                r_[i * 4] = a4.x; r_[i * 4 + 1] = a4.y; r_[i * 4 + 2] = a4.z; r_[i * 4 + 3] = a4.w;
                float4 b4 = ((const float4*)sb)[ch * 4 + i];
                s_[i * 4] = b4.x; s_[i * 4 + 1] = b4.y; s_[i * 4 + 2] = b4.z; s_[i * 4 + 3] = b4.w;
                float4 c4 = ((const float4*)tb)[ch * 4 + i];
                t_[i * 4] = c4.x; t_[i * 4 + 1] = c4.y; t_[i * 4 + 2] = c4.z; t_[i * 4 + 3] = c4.w;
                float4 d4 = ((const float4*)ub)[ch * 4 + i];
                u_[i * 4] = d4.x; u_[i * 4 + 1] = d4.y; u_[i * 4 + 2] = d4.z; u_[i * 4 + 3] = d4.w;
            }
            float rp = rb[p], rp1 = rb[p + 1], sp1 = sb[p + 1];
            float rT = rb[p + 2], sT = sb[p + 2];
            float rU = rb[p + 3], sU = sb[p + 3];
            float tp2 = tb[p + 2], tp3 = tb[p + 3], up3 = ub[p + 3];
            float gr = rb[row], gs = sb[row];
            float tr = tb[row], ur = ub[row];

            // ---- phase A (pivots p, p+1) ----
            float i1 = 1.f / rp;
            float al = rp1 * i1;
            float i2 = 1.f / (sp1 - al * rp1);
            float b2T = (sT - al * rT) * i2;
            float caT = al * b2T - rT * i1, cbT = -b2T;
            float b2U = (sU - al * rU) * i2;
            float caU = al * b2U - rU * i1, cbU = -b2U;
            float c0, ca, cb;
            if (row == p) {
                c0 = 0.f; ca = i1 + al * al * i2; cb = -al * i2;
            } else if (row == p + 1) {
                c0 = 0.f; ca = -al * i2; cb = i2;
            } else {
                float b2 = (gs - al * gr) * i2;
                c0 = 1.f; ca = al * b2 - gr * i1; cb = -b2;
            }
#pragma unroll
            for (int i = 0; i < 16; ++i) {
                float upd = c0 * m[i] + ca * r_[i] + cb * s_[i];
                int col = ch * 16 + i;
                upd = (col == p) ? -ca : upd;
                upd = (col == p + 1) ? -cb : upd;
                m[i] = upd;
            }
#pragma unroll
            for (int i = 0; i < 16; ++i) {
                float tv = t_[i] + caT * r_[i] + cbT * s_[i];
                float uv = u_[i] + caU * r_[i] + cbU * s_[i];
                int col = ch * 16 + i;
                tv = (col == p) ? -caT : tv;
                tv = (col == p + 1) ? -cbT : tv;
                uv = (col == p) ? -caU : uv;
                uv = (col == p + 1) ? -cbU : uv;
                t_[i] = tv;
                u_[i] = uv;
            }

            // ---- phase B (pivots p+2, p+3 of M_A) ----
            float rpB = tp2 + caT * rT + cbT * sT;
            float rp3B = tp3 + caT * rU + cbT * sU;
            float sp3B = up3 + caU * rU + cbU * sU;
            float grB, gsB;
            if (row == p) {
                grB = -caT; gsB = -caU;
            } else if (row == p + 1) {
                grB = -cbT; gsB = -cbU;
            } else {
                grB = tr + caT * gr + cbT * gs;
                gsB = ur + caU * gr + cbU * gs;
            }
            float i1B = 1.f / rpB;
            float alB = rp3B * i1B;
            float i2B = 1.f / (sp3B - alB * rp3B);
            float c0B, cc, cd;
            if (row == p + 2) {
                c0B = 0.f; cc = i1B + alB * alB * i2B; cd = -alB * i2B;
            } else if (row == p + 3) {
                c0B = 0.f; cc = -alB * i2B; cd = i2B;
            } else {
                float b2B = (gsB - alB * grB) * i2B;
                c0B = 1.f; cc = alB * b2B - grB * i1B; cd = -b2B;
            }
#pragma unroll
            for (int i = 0; i < 16; ++i) {
                float upd = c0B * m[i] + cc * t_[i] + cd * u_[i];
                int col = ch * 16 + i;
                upd = (col == p + 2) ? -cc : upd;
                upd = (col == p + 3) ? -cd : upd;
                m[i] = upd;
            }

            if (pp < 15) {
                if (row >= p + 4 && row < p + 8) {
                    float* dst = Rq + ((pp + 1) & 1) * 256 + (row - (p + 4)) * 64;
#pragma unroll
                    for (int i = 0; i < 4; ++i)
                        ((float4*)dst)[ch * 4 + i] =
                            make_float4(m[i * 4], m[i * 4 + 1], m[i * 4 + 2], m[i * 4 + 3]);
                }
            }
            __syncthreads();
        }

        // ---- paired Sherman-Morrison scan (H = -M), CS=64 -> 32 rounds ----
        for (int tp = 0; tp < 32; ++tp) {
            const int ta = 2 * tp, tb2 = 2 * tp + 1;
            const int par = tp & 1;
            float pu = 0.f, pw = 0.f, pza = 0.f, pzb = 0.f;
#pragma unroll
            for (int i = 0; i < 4; ++i) {
                float4 xa = ((const float4*)(Xs + ta * 64))[ch * 4 + i];
                float4 xb = ((const float4*)(Xs + tb2 * 64))[ch * 4 + i];
                float4 qa = ((const float4*)(Qs + ta * 64))[ch * 4 + i];
                float4 q4 = ((const float4*)(Qs + tb2 * 64))[ch * 4 + i];
                pu += m[i * 4] * xa.x + m[i * 4 + 1] * xa.y + m[i * 4 + 2] * xa.z + m[i * 4 + 3] * xa.w;
                pw += m[i * 4] * xb.x + m[i * 4 + 1] * xb.y + m[i * 4 + 2] * xb.z + m[i * 4 + 3] * xb.w;
                pza += m[i * 4] * qa.x + m[i * 4 + 1] * qa.y + m[i * 4 + 2] * qa.z + m[i * 4 + 3] * qa.w;
                pzb += m[i * 4] * q4.x + m[i * 4 + 1] * q4.y + m[i * 4 + 2] * q4.z + m[i * 4 + 3] * q4.w;
            }
            pu += __shfl_xor(pu, 1); pu += __shfl_xor(pu, 2);
            pw += __shfl_xor(pw, 1); pw += __shfl_xor(pw, 2);
            pza += __shfl_xor(pza, 1); pza += __shfl_xor(pza, 2);
            pzb += __shfl_xor(pzb, 1); pzb += __shfl_xor(pzb, 2);
            float u = -pu, w = -pw, za = -pza, zb = -pzb;
            float* rbufP = Rq + par * 256;
            float* sbufP = Rq + par * 256 + 64;
            if (ch == 0) rbufP[row] = u;
            if (ch == 1) sbufP[row] = w;
            float a_ = Xs[ta * 64 + row], b_ = Xs[tb2 * 64 + row];
            float qa_ = Qs[ta * 64 + row], qb_ = Qs[tb2 * 64 + row];
            float d0 = a_ * u, d1 = b_ * u, d2 = b_ * w;
            float d3 = qa_ * u, d4 = qb_ * u, d5 = qb_ * w;
#pragma unroll
            for (int off = 32; off; off >>= 1) {
                d0 += __shfl_xor(d0, off); d1 += __shfl_xor(d1, off);
                d2 += __shfl_xor(d2, off); d3 += __shfl_xor(d3, off);
                d4 += __shfl_xor(d4, off); d5 += __shfl_xor(d5, off);
            }
            if ((tid & 63) == 0) {
                red[par * 24 + 0 * 4 + wav] = d0; red[par * 24 + 1 * 4 + wav] = d1;
                red[par * 24 + 2 * 4 + wav] = d2; red[par * 24 + 3 * 4 + wav] = d3;
                red[par * 24 + 4 * 4 + wav] = d4; red[par * 24 + 5 * 4 + wav] = d5;
            }
            __syncthreads();
            const float* rp_ = red + par * 24;
            float saa = 0.25f * (rp_[0] + rp_[1] + rp_[2] + rp_[3]);
            float sab = 0.25f * (rp_[4] + rp_[5] + rp_[6] + rp_[7]);
            float sbb = 0.25f * (rp_[8] + rp_[9] + rp_[10] + rp_[11]);
            float c1  = 0.25f * (rp_[12] + rp_[13] + rp_[14] + rp_[15]);
            float c2  = 0.25f * (rp_[16] + rp_[17] + rp_[18] + rp_[19]);
            float c3  = 0.25f * (rp_[20] + rp_[21] + rp_[22] + rp_[23]);
            float k1 = 1.f / (1.f + saa);
            float al2 = sab * k1;
            float k2 = 1.f / (1.f + sbb - sab * al2);
            float vr = w - al2 * u;
            if (ch == 0) Po[ta * 64 + row] = za - (c1 * k1) * u;
            if (ch == 1) Po[tb2 * 64 + row] = zb - (c2 * k1) * u - (k2 * (c3 - al2 * c2)) * vr;
            float cu = k1 * u - al2 * k2 * vr;
            float cw = k2 * vr;
#pragma unroll
            for (int i = 0; i < 4; ++i) {
                float4 uj = ((const float4*)rbufP)[ch * 4 + i];
                float4 wj = ((const float4*)sbufP)[ch * 4 + i];
                m[i * 4 + 0] += cu * uj.x + cw * wj.x;
                m[i * 4 + 1] += cu * uj.y + cw * wj.y;
                m[i * 4 + 2] += cu * uj.z + cw * wj.z;
                m[i * 4 + 3] += cu * uj.w + cw * wj.w;
            }
        }
        __syncthreads();

        float4* po4 = (float4*)(preds + ((size_t)chain * T_SEQ + chunk * CS) * DH);
#pragma unroll
        for (int j = 0; j < 4; ++j)
            po4[j * 256 + tid] = ((const float4*)Po)[j * 256 + tid];
    } else {
        // ---- kv_gram: D_ck = V_ck^T K_ck ----
        int kb = bid - nInv;
        int chain = kb >> 4, ck = kb & 15;
        float* Vs = smem;
        float* Ks2 = smem + 4096;
        const float4* Vb = (const float4*)(v + ((size_t)chain * T_SEQ + ck * 64) * DH);
        const float4* Kb = (const float4*)(Kv + ((size_t)chain * T_SEQ + ck * 64) * DH);
#pragma unroll
        for (int i = 0; i < 4; ++i) {
            ((float4*)Vs)[i * 256 + tid] = Vb[i * 256 + tid];
            ((float4*)Ks2)[i * 256 + tid] = Kb[i * 256 + tid];
        }
        __syncthreads();

        int tx = tid & 15, ty = tid >> 4;
        float acc[4][4];
#pragma unroll
        for (int i = 0; i < 4; ++i)
#pragma unroll
            for (int j = 0; j < 4; ++j) acc[i][j] = 0.f;

#pragma unroll 4
        for (int t = 0; t < 64; ++t) {
            float a_[4], b_[4];
#pragma unroll
            for (int i = 0; i < 4; ++i) a_[i] = Vs[t * 64 + ty * 4 + i];
#pragma unroll
            for (int j = 0; j < 4; ++j) b_[j] = Ks2[t * 64 + tx * 4 + j];
#pragma unroll
            for (int i = 0; i < 4; ++i)
#pragma unroll
                for (int j = 0; j < 4; ++j) acc[i][j] += a_[i] * b_[j];
        }

        float* dp = D + ((size_t)chain * ACH + ck) * 4096;
#pragma unroll
        for (int i = 0; i < 4; ++i)
            *(float4*)(dp + (ty * 4 + i) * 64 + tx * 4) =
                make_float4(acc[i][0], acc[i][1], acc[i][2], acc[i][3]);
    }
}

// ---------------------------------------------------------------------------
// exclusive prefix over ACH chunks — register-staged
// ---------------------------------------------------------------------------
__global__ __launch_bounds__(256) void kv_prefix(float* __restrict__ d) {
    int gid = blockIdx.x * 256 + threadIdx.x;
    int chain = gid >> 12, elem = gid & 4095;
    float* p = d + (size_t)chain * ACH * 4096 + elem;
    float vals[ACH];
#pragma unroll
    for (int c = 0; c < ACH; ++c) vals[c] = p[(size_t)c * 4096];
    float run = 0.f;
#pragma unroll
    for (int c = 0; c < ACH; ++c) {
        float t = vals[c];
        vals[c] = run;
        run += t;
    }
#pragma unroll
    for (int c = 0; c < ACH; ++c) p[(size_t)c * 4096] = vals[c];
}

// ---------------------------------------------------------------------------
// attn_wot: blocks <256 -> attention chunk (epilogue splits into permuted
// bf16 A2); blocks >=256 -> Wo transpose+split (q region is dead by now).
// ---------------------------------------------------------------------------
__global__ __launch_bounds__(256) void attn_wot(
    const float* __restrict__ P, const float* __restrict__ V,
    const float* __restrict__ Kv, const float* __restrict__ C,
    ushort* __restrict__ A2_hi, ushort* __restrict__ A2_lo,
    const float* __restrict__ Wo,
    ushort* __restrict__ Wot_hi, ushort* __restrict__ Wot_lo) {
    __shared__ float4 smem4[3072];   // 48KB union
    int bid = blockIdx.x;
    int tid = threadIdx.x;

    if (bid < 256) {
        int ck = bid & 15, bh = bid >> 4;
        int tx = tid & 15, ty = tid >> 4;
        float4* Ps = smem4;
        float4* Bs = smem4 + 1024;
        float4* Ks = smem4 + 2048;

        int lr = tid >> 2, lc = tid & 3;
        const float4* Pb = (const float4*)(P + ((size_t)bh * T_SEQ + ck * 64) * DH);
        const float4* Vb = (const float4*)(V + ((size_t)bh * T_SEQ + ck * 64) * DH);
        const float4* Kb = (const float4*)(Kv + ((size_t)bh * T_SEQ + ck * 64) * DH);
        const float4* Cb = (const float4*)(C + ((size_t)bh * ACH + ck) * 4096);
#pragma unroll
        for (int i = 0; i < 4; ++i) {
            Ps[swz4(lr, lc + i * 4)] = Pb[lr * 16 + lc + i * 4];
            Bs[swz4(lr, lc + i * 4)] = Cb[lr * 16 + lc + i * 4];
            Ks[swz4(lr, lc + i * 4)] = Kb[lr * 16 + lc + i * 4];
        }

        float4 o[4];
        o[0] = o[1] = o[2] = o[3] = make_float4(0.f, 0.f, 0.f, 0.f);
        __syncthreads();

        const float* Pf = (const float*)Ps;
#pragma unroll 4
        for (int j = 0; j < 64; ++j) {
            float4 b4 = Bs[swz4(j, tx)];
#pragma unroll
            for (int i = 0; i < 4; ++i) {
                float s = Pf[swz4(ty * 4 + i, j >> 2) * 4 + (j & 3)];
                fma4(o[i], s, b4);
            }
        }
        __syncthreads();

#pragma unroll
        for (int i = 0; i < 4; ++i)
            Bs[swz4(lr, lc + i * 4)] = Vb[lr * 16 + lc + i * 4];
        __syncthreads();

        float4 sa[4][4];
#pragma unroll
        for (int i = 0; i < 4; ++i)
#pragma unroll
            for (int j = 0; j < 4; ++j) sa[i][j] = make_float4(0.f, 0.f, 0.f, 0.f);
#pragma unroll
        for (int d4 = 0; d4 < 16; ++d4) {
            float4 a[4], b[4];
#pragma unroll
            for (int i = 0; i < 4; ++i) a[i] = Ps[swz4(ty * 4 + i, d4)];
#pragma unroll
            for (int j = 0; j < 4; ++j) b[j] = Bs[swz4(tx * 4 + j, d4)];
#pragma unroll
            for (int i = 0; i < 4; ++i)
#pragma unroll
                for (int j = 0; j < 4; ++j) {
                    sa[i][j].x += a[i].x * b[j].x;
                    sa[i][j].y += a[i].y * b[j].y;
                    sa[i][j].z += a[i].z * b[j].z;
                    sa[i][j].w += a[i].w * b[j].w;
                }
        }
        __syncthreads();

#pragma unroll
        for (int i = 0; i < 4; ++i) {
            int m = ty * 4 + i;
            float sv[4];
#pragma unroll
            for (int j = 0; j < 4; ++j) {
                float s = sa[i][j].x + sa[i][j].y + sa[i][j].z + sa[i][j].w;
                if ((tx * 4 + j) > m) s = 0.f;
                sv[j] = s;
            }
            Bs[swz4(m, tx)] = make_float4(sv[0], sv[1], sv[2], sv[3]);
        }
        __syncthreads();

        const float* Sf = (const float*)Bs;
#pragma unroll 4
        for (int j = 0; j < 64; ++j) {
            float4 b4 = Ks[swz4(j, tx)];
#pragma unroll
            for (int i = 0; i < 4; ++i) {
                float s = Sf[swz4(ty * 4 + i, j >> 2) * 4 + (j & 3)];
                fma4(o[i], s, b4);
            }
        }

        int kkb = ((bh & 7) << 6) + tx * 4;
#pragma unroll
        for (int i = 0; i < 4; ++i) {
            int t = ck * 64 + ty * 4 + i;
            size_t mrow = (size_t)((bh >> 3) << 10) + t;
            ushort4 h, l;
            split2(o[i].x, h.x, l.x);
            split2(o[i].y, h.y, l.y);
            split2(o[i].z, h.z, l.z);
            split2(o[i].w, h.w, l.w);
            *(ushort4*)&A2_hi[mrow * 512 + kkb] = h;
            *(ushort4*)&A2_lo[mrow * 512 + kkb] = l;
        }
    } else {
        float* Tf = (float*)smem4;       // [64][65]
        int wb = bid - 256;              // 0..63
        int kk0 = (wb >> 3) * 64, n0 = (wb & 7) * 64;
#pragma unroll
        for (int i = 0; i < 4; ++i) {
            int rl = i * 16 + (tid >> 4);
            int rs = rl * 8 + (kk0 >> 6);   // (d,H) interleave remap
            float4 vv = *(const float4*)&Wo[(size_t)rs * 512 + n0 + (tid & 15) * 4];
            Tf[rl * 65 + (tid & 15) * 4 + 0] = vv.x;
            Tf[rl * 65 + (tid & 15) * 4 + 1] = vv.y;
            Tf[rl * 65 + (tid & 15) * 4 + 2] = vv.z;
            Tf[rl * 65 + (tid & 15) * 4 + 3] = vv.w;
        }
        __syncthreads();
        int nl = tid >> 2, kl = (tid & 3) * 16;
#pragma unroll
        for (int j4 = 0; j4 < 4; ++j4) {
            ushort4 h4, l4;
            split2(Tf[(kl + j4 * 4 + 0) * 65 + nl], h4.x, l4.x);
            split2(Tf[(kl + j4 * 4 + 1) * 65 + nl], h4.y, l4.y);
            split2(Tf[(kl + j4 * 4 + 2) * 65 + nl], h4.z, l4.z);
            split2(Tf[(kl + j4 * 4 + 3) * 65 + nl], h4.w, l4.w);
            size_t dst = (size_t)(n0 + nl) * 512 + kk0 + kl + j4 * 4;
            *(ushort4*)&Wot_hi[dst] = h4;
            *(ushort4*)&Wot_lo[dst] = l4;
        }
    }
}

extern "C" void kernel_launch(void* const* d_in, const int* in_sizes, int n_in,
                              void* d_out, int out_size, void* d_ws, size_t ws_size,
                              hipStream_t stream) {
    const float* x = (const float*)d_in[0];
    const float* Wq = (const float*)d_in[1];
    const float* Wk = (const float*)d_in[2];
    const float* Wv = (const float*)d_in[3];
    const float* Wo = (const float*)d_in[4];
    const float* lambdas = (const float*)d_in[5];
    float* out = (float*)d_out;

    float* ws = (float*)d_ws;
    const size_t SZ = (size_t)NB * NH * T_SEQ * DH;  // 1048576 floats (4 MB)
    float* q = ws;                 // [0,1M); Wot lives here after invscan
    float* k = ws + SZ;            // [1M,2M)
    float* v = ws + 2 * SZ;        // [2M,3M)
    float* preds = ws + 3 * SZ;    // slotD: x hi/lo -> preds
    ushort* x_hi = (ushort*)(ws + 3 * SZ);
    ushort* x_lo = (ushort*)(ws + 3 * SZ + SZ / 2);
    float* g = ws + 4 * SZ;        // [4M,5M): Wt -> g (1M floats with NCH=16)
    ushort* Wt_hi = (ushort*)(ws + 4 * SZ);
    ushort* Wt_lo = (ushort*)(ws + 4 * SZ + 393216);
    ushort* A2_hi = (ushort*)(ws + 5 * SZ);            // [5M,6M) after invscan
    ushort* A2_lo = (ushort*)(ws + 5 * SZ + SZ / 2);
    ushort* Wot_hi = (ushort*)ws;                      // q region (dead)
    ushort* Wot_lo = (ushort*)(ws + 131072);

    bool big = ws_size >= (size_t)7 * SZ * sizeof(float);
    float* dbuf = big ? (ws + 6 * SZ) : g;

    prep_qkv<<<dim3(8, 8, 4), 256, 0, stream>>>(x, Wq, Wk, Wv,
                                                x_hi, x_lo, Wt_hi, Wt_lo);
    mfma_gemm<0><<<dim3(16, 8, 3), 256, 0, stream>>>(
        x_hi, x_lo, Wt_hi, Wt_lo, q, k, v);
    gram_kernel<<<dim3(NCHAIN, NCH), 256, 0, stream>>>(v, g);
    prefix_kernel<<<dim3(256), 256, 0, stream>>>(g);
    if (big) {
        invscan_kv<<<dim3(NCHAIN * NCH + NCHAIN * ACH), 256, 0, stream>>>(
            NCHAIN * NCH, g, v, q, lambdas, preds, k, dbuf);
    } else {
        invscan_kv<<<dim3(NCHAIN * NCH), 256, 0, stream>>>(
            NCHAIN * NCH, g, v, q, lambdas, preds, k, dbuf);
        invscan_kv<<<dim3(NCHAIN * ACH), 256, 0, stream>>>(
            0, g, v, q, lambdas, preds, k, dbuf);
    }
    kv_prefix<<<dim3(256), 256, 0, stream>>>(dbuf);
    attn_wot<<<dim3(320), 256, 0, stream>>>(preds, v, k, dbuf, A2_hi, A2_lo,
                                            Wo, Wot_hi, Wot_lo);
    mfma_gemm<1><<<dim3(16, 8, 1), 256, 0, stream>>>(
        (const ushort*)A2_hi, (const ushort*)A2_lo, Wot_hi, Wot_lo,
        out, out, out);
}

// Round 18
// 124.636 us; speedup vs baseline: 1.0413x; 1.0413x over previous
//
#include <hip/hip_runtime.h>

#define T_SEQ 1024
#define DH 64
#define NH 8
#define NB 2
#define EMB 512
#define CS 32      // tokens per scan chunk
#define NCH 32     // chunks per chain
#define ACH 16     // attention chunks per chain (64 tokens each)
#define NCHAIN 16  // B*H

typedef __attribute__((ext_vector_type(8))) short bf16x8;
typedef __attribute__((ext_vector_type(4))) float f32x4;

__device__ __forceinline__ int swz4(int r, int c4) {
    return r * 16 + ((c4 ^ (r >> 2)) & 15);
}

__device__ __forceinline__ void fma4(float4& o, float s, const float4& b) {
    o.x += s * b.x; o.y += s * b.y; o.z += s * b.z; o.w += s * b.w;
}

__device__ __forceinline__ ushort f2bf(float f) {
    unsigned u = __float_as_uint(f);
    return (ushort)((u + 0x7FFFu + ((u >> 16) & 1u)) >> 16);
}
__device__ __forceinline__ float bf2f(ushort h) {
    return __uint_as_float(((unsigned)h) << 16);
}
__device__ __forceinline__ void split2(float f, ushort& hi, ushort& lo) {
    hi = f2bf(f);
    lo = f2bf(f - bf2f(hi));
}

// ---------------------------------------------------------------------------
// prep_qkv: z<3 -> transpose+split W{q,k,v}; z==3 -> split x.
// ---------------------------------------------------------------------------
__global__ __launch_bounds__(256) void prep_qkv(
    const float* __restrict__ x, const float* __restrict__ W0,
    const float* __restrict__ W1, const float* __restrict__ W2,
    ushort* __restrict__ x_hi, ushort* __restrict__ x_lo,
    ushort* __restrict__ Wt_hi, ushort* __restrict__ Wt_lo) {
    int zz = blockIdx.z;
    int t = threadIdx.x;
    __shared__ float T[64][65];
    if (zz < 3) {
        const float* W = (zz == 0) ? W0 : (zz == 1) ? W1 : W2;
        ushort* hi = Wt_hi + (size_t)zz * 262144;
        ushort* lo = Wt_lo + (size_t)zz * 262144;
        int kk0 = blockIdx.x * 64, n0 = blockIdx.y * 64;
#pragma unroll
        for (int i = 0; i < 4; ++i) {
            int rl = i * 16 + (t >> 4);
            float4 vv = *(const float4*)&W[(size_t)(kk0 + rl) * 512 + n0 + (t & 15) * 4];
            T[rl][(t & 15) * 4 + 0] = vv.x;
            T[rl][(t & 15) * 4 + 1] = vv.y;
            T[rl][(t & 15) * 4 + 2] = vv.z;
            T[rl][(t & 15) * 4 + 3] = vv.w;
        }
        __syncthreads();
        int nl = t >> 2, kl = (t & 3) * 16;
#pragma unroll
        for (int j4 = 0; j4 < 4; ++j4) {
            ushort4 h4, l4;
            split2(T[kl + j4 * 4 + 0][nl], h4.x, l4.x);
            split2(T[kl + j4 * 4 + 1][nl], h4.y, l4.y);
            split2(T[kl + j4 * 4 + 2][nl], h4.z, l4.z);
            split2(T[kl + j4 * 4 + 3][nl], h4.w, l4.w);
            size_t dst = (size_t)(n0 + nl) * 512 + kk0 + kl + j4 * 4;
            *(ushort4*)&hi[dst] = h4;
            *(ushort4*)&lo[dst] = l4;
        }
    } else {
        int bid = blockIdx.y * 8 + blockIdx.x;
        const float4* in = (const float4*)x;
        ushort4* hi = (ushort4*)x_hi;
        ushort4* lo = (ushort4*)x_lo;
#pragma unroll
        for (int i = 0; i < 16; ++i) {
            int id = (bid * 16 + i) * 256 + t;
            float4 xv = in[id];
            ushort4 h, l;
            split2(xv.x, h.x, l.x);
            split2(xv.y, h.y, l.y);
            split2(xv.z, h.z, l.z);
            split2(xv.w, h.w, l.w);
            hi[id] = h;
            lo[id] = l;
        }
    }
}

// ---------------------------------------------------------------------------
// MFMA GEMM: C[2048][512] = A * B, bf16 hi/lo split, Bt[n][k] transposed.
// ---------------------------------------------------------------------------
template <int MODE>
__global__ __launch_bounds__(256) void mfma_gemm(
    const ushort* __restrict__ Ahi, const ushort* __restrict__ Alo,
    const ushort* __restrict__ Bth, const ushort* __restrict__ Btl,
    float* __restrict__ o0, float* __restrict__ o1, float* __restrict__ o2) {
    int bm = blockIdx.x, bn = blockIdx.y, zz = blockIdx.z;
    const ushort* Bh = Bth + (size_t)zz * 262144;
    const ushort* Bl = Btl + (size_t)zz * 262144;
    float* out = (MODE == 0) ? ((zz == 0) ? o0 : (zz == 1) ? o1 : o2) : o0;

    __shared__ ushort Ash[128 * 40];
    __shared__ ushort Asl[128 * 40];
    __shared__ ushort Bsh[64 * 40];
    __shared__ ushort Bsl[64 * 40];

    int tid = threadIdx.x;
    int lane = tid & 63, wid = tid >> 6;
    int wm = wid >> 1, wn = wid & 1;
    int fr = lane & 15, fk = (lane >> 4) * 8;
    int sr = tid >> 2, sc = (tid & 3) * 8;

    f32x4 zero = {0.f, 0.f, 0.f, 0.f};
    f32x4 acc[4][2];
#pragma unroll
    for (int f = 0; f < 4; ++f)
#pragma unroll
        for (int g = 0; g < 2; ++g) acc[f][g] = zero;

    const ushort* gAh = Ahi + (size_t)(bm * 128 + sr) * 512 + sc;
    const ushort* gAl = Alo + (size_t)(bm * 128 + sr) * 512 + sc;
    const ushort* gBh = Bh + (size_t)(bn * 64 + sr) * 512 + sc;
    const ushort* gBl = Bl + (size_t)(bn * 64 + sr) * 512 + sc;

    for (int k0 = 0; k0 < 512; k0 += 32) {
        uint4 a0 = *(const uint4*)(gAh + k0);
        uint4 a1 = *(const uint4*)(gAh + 64 * 512 + k0);
        uint4 a2 = *(const uint4*)(gAl + k0);
        uint4 a3 = *(const uint4*)(gAl + 64 * 512 + k0);
        uint4 b0 = *(const uint4*)(gBh + k0);
        uint4 b1 = *(const uint4*)(gBl + k0);
        __syncthreads();
        *(uint4*)&Ash[sr * 40 + sc] = a0;
        *(uint4*)&Ash[(sr + 64) * 40 + sc] = a1;
        *(uint4*)&Asl[sr * 40 + sc] = a2;
        *(uint4*)&Asl[(sr + 64) * 40 + sc] = a3;
        *(uint4*)&Bsh[sr * 40 + sc] = b0;
        *(uint4*)&Bsl[sr * 40 + sc] = b1;
        __syncthreads();
        bf16x8 ah[4], al[4], bh[2], blo[2];
#pragma unroll
        for (int f = 0; f < 4; ++f) {
            int r = wm * 64 + f * 16 + fr;
            ah[f] = *(const bf16x8*)&Ash[r * 40 + fk];
            al[f] = *(const bf16x8*)&Asl[r * 40 + fk];
        }
#pragma unroll
        for (int g = 0; g < 2; ++g) {
            int r = wn * 32 + g * 16 + fr;
            bh[g] = *(const bf16x8*)&Bsh[r * 40 + fk];
            blo[g] = *(const bf16x8*)&Bsl[r * 40 + fk];
        }
#pragma unroll
        for (int f = 0; f < 4; ++f)
#pragma unroll
            for (int g = 0; g < 2; ++g) {
                acc[f][g] = __builtin_amdgcn_mfma_f32_16x16x32_bf16(
                    ah[f], bh[g], acc[f][g], 0, 0, 0);
                acc[f][g] = __builtin_amdgcn_mfma_f32_16x16x32_bf16(
                    ah[f], blo[g], acc[f][g], 0, 0, 0);
                acc[f][g] = __builtin_amdgcn_mfma_f32_16x16x32_bf16(
                    al[f], bh[g], acc[f][g], 0, 0, 0);
            }
    }

    int rbase = (lane >> 4) * 4;
#pragma unroll
    for (int f = 0; f < 4; ++f)
#pragma unroll
        for (int g = 0; g < 2; ++g)
#pragma unroll
            for (int j = 0; j < 4; ++j) {
                int m = bm * 128 + wm * 64 + f * 16 + rbase + j;
                int n = bn * 64 + wn * 32 + g * 16 + (lane & 15);
                float val = acc[f][g][j];
                if (MODE == 0) {
                    int b = m >> 10, tt = m & 1023;
                    int h = n >> 6, d = n & 63;
                    out[(((size_t)(b * 8 + h) * 1024 + tt) << 6) + d] = val;
                } else {
                    out[(size_t)m * 512 + n] = val;
                }
            }
}

// ---------------------------------------------------------------------------
// per-chunk Gram G = X^T X (64x64, CS tokens)
// ---------------------------------------------------------------------------
__global__ __launch_bounds__(256) void gram_kernel(
    const float* __restrict__ v, float* __restrict__ g) {
    int chain = blockIdx.x, chunk = blockIdx.y;
    const float* X = v + ((size_t)chain * T_SEQ + chunk * CS) * DH;
    __shared__ float Xs[CS * 64];
    int tid = threadIdx.x;
#pragma unroll
    for (int i = 0; i < (CS * 16) / 256; ++i)
        ((float4*)Xs)[i * 256 + tid] = ((const float4*)X)[i * 256 + tid];
    __syncthreads();

    int tx = tid & 15, ty = tid >> 4;
    float acc[4][4];
#pragma unroll
    for (int i = 0; i < 4; ++i)
#pragma unroll
        for (int j = 0; j < 4; ++j) acc[i][j] = 0.f;

#pragma unroll 4
    for (int t = 0; t < CS; ++t) {
        float a_[4], b_[4];
#pragma unroll
        for (int i = 0; i < 4; ++i) a_[i] = Xs[t * 64 + ty * 4 + i];
#pragma unroll
        for (int j = 0; j < 4; ++j) b_[j] = Xs[t * 64 + tx * 4 + j];
#pragma unroll
        for (int i = 0; i < 4; ++i)
#pragma unroll
            for (int j = 0; j < 4; ++j) acc[i][j] += a_[i] * b_[j];
    }

    float* gp = g + ((size_t)chain * NCH + chunk) * 4096;
#pragma unroll
    for (int i = 0; i < 4; ++i)
        *(float4*)(gp + (ty * 4 + i) * 64 + tx * 4) =
            make_float4(acc[i][0], acc[i][1], acc[i][2], acc[i][3]);
}

// ---------------------------------------------------------------------------
// exclusive prefix over NCH chunks — register-staged
// ---------------------------------------------------------------------------
__global__ __launch_bounds__(256) void prefix_kernel(float* __restrict__ g) {
    int gid = blockIdx.x * 256 + threadIdx.x;
    int chain = gid >> 12, elem = gid & 4095;
    float* p = g + (size_t)chain * NCH * 4096 + elem;
    float vals[NCH];
#pragma unroll
    for (int c = 0; c < NCH; ++c) vals[c] = p[(size_t)c * 4096];
    float run = 0.f;
#pragma unroll
    for (int c = 0; c < NCH; ++c) {
        float t = vals[c];
        vals[c] = run;
        run += t;
    }
#pragma unroll
    for (int c = 0; c < NCH; ++c) p[(size_t)c * 4096] = vals[c];
}

// ---------------------------------------------------------------------------
// invscan_kv: heterogeneous grid. Blocks < nInv: RANK-4 GJ sweep (16 rounds)
// + rank-2 SM scan (16 rounds). Blocks >= nInv: kv_gram. 32KB LDS union.
// ---------------------------------------------------------------------------
__global__ __launch_bounds__(256) void invscan_kv(
    int nInv,
    const float* __restrict__ g, const float* __restrict__ v,
    const float* __restrict__ q, const float* __restrict__ lambdas,
    float* __restrict__ preds,
    const float* __restrict__ Kv, float* __restrict__ D) {
    __shared__ float smem[8192];
    int bid = blockIdx.x;
    int tid = threadIdx.x;

    if (bid < nInv) {
        int chain = bid >> 5, chunk = bid & 31;
        int row = tid >> 2, ch = tid & 3, wav = tid >> 6;
        float lam = lambdas[chain & (NH - 1)];

        float* Xs = smem;                 // 2048
        float* Qs = smem + 2048;          // 2048
        float* Po = smem + 4096;          // 2048
        float* Rq = smem + 6144;          // [2][4][64] = 512
        float* red = smem + 6656;         // [2][6][4] = 48

        float m[16];
        {
            const float4* gp = (const float4*)(g + ((size_t)chain * NCH + chunk) * 4096);
#pragma unroll
            for (int i = 0; i < 4; ++i) {
                float4 t4 = gp[row * 16 + ch * 4 + i];
                m[i * 4 + 0] = t4.x; m[i * 4 + 1] = t4.y;
                m[i * 4 + 2] = t4.z; m[i * 4 + 3] = t4.w;
            }
        }
#pragma unroll
        for (int i = 0; i < 16; ++i)
            if (ch * 16 + i == row) m[i] += lam;

        const float4* vb = (const float4*)(v + ((size_t)chain * T_SEQ + chunk * CS) * DH);
        const float4* qb = (const float4*)(q + ((size_t)chain * T_SEQ + chunk * CS) * DH);
        ((float4*)Xs)[tid] = vb[tid];
        ((float4*)Xs)[256 + tid] = vb[256 + tid];
        ((float4*)Qs)[tid] = qb[tid];
        ((float4*)Qs)[256 + tid] = qb[256 + tid];

        if (row < 4) {
#pragma unroll
            for (int i = 0; i < 4; ++i)
                ((float4*)(Rq + row * 64))[ch * 4 + i] =
                    make_float4(m[i * 4], m[i * 4 + 1], m[i * 4 + 2], m[i * 4 + 3]);
        }
        __syncthreads();

        // ---- RANK-4 GJ sweep: pivots (p..p+3), 16 rounds ----
#pragma unroll
        for (int pp = 0; pp < 16; ++pp) {
            const int p = 4 * pp;
            const float* rb = Rq + (pp & 1) * 256;
            const float* sb = rb + 64;
            const float* tb = rb + 128;
            const float* ub = rb + 192;
            float r_[16], s_[16], t_[16], u_[16];
#pragma unroll
            for (int i = 0; i < 4; ++i) {
                float4 a4 = ((const float4*)rb)[ch * 4 + i];
                r_[i * 4] = a4.x; r_[i * 4 + 1] = a4.y; r_[i * 4 + 2] = a4.z; r_[i * 4 + 3] = a4.w;
                float4 b4 = ((const float4*)sb)[ch * 4 + i];
                s_[i * 4] = b4.x; s_[i * 4 + 1] = b4.y; s_[i * 4 + 2] = b4.z; s_[i * 4 + 3] = b4.w;
                float4 c4 = ((const float4*)tb)[ch * 4 + i];
                t_[i * 4] = c4.x; t_[i * 4 + 1] = c4.y; t_[i * 4 + 2] = c4.z; t_[i * 4 + 3] = c4.w;
                float4 d4 = ((const float4*)ub)[ch * 4 + i];
                u_[i * 4] = d4.x; u_[i * 4 + 1] = d4.y; u_[i * 4 + 2] = d4.z; u_[i * 4 + 3] = d4.w;
            }
            float rp = rb[p], rp1 = rb[p + 1], sp1 = sb[p + 1];
            float rT = rb[p + 2], sT = sb[p + 2];
            float rU = rb[p + 3], sU = sb[p + 3];
            float tp2 = tb[p + 2], tp3 = tb[p + 3], up3 = ub[p + 3];
            float gr = rb[row], gs = sb[row];
            float tr = tb[row], ur = ub[row];

            float i1 = 1.f / rp;
            float al = rp1 * i1;
            float i2 = 1.f / (sp1 - al * rp1);
            float b2T = (sT - al * rT) * i2;
            float caT = al * b2T - rT * i1, cbT = -b2T;
            float b2U = (sU - al * rU) * i2;
            float caU = al * b2U - rU * i1, cbU = -b2U;
            float c0, ca, cb;
            if (row == p) {
                c0 = 0.f; ca = i1 + al * al * i2; cb = -al * i2;
            } else if (row == p + 1) {
                c0 = 0.f; ca = -al * i2; cb = i2;
            } else {
                float b2 = (gs - al * gr) * i2;
                c0 = 1.f; ca = al * b2 - gr * i1; cb = -b2;
            }
#pragma unroll
            for (int i = 0; i < 16; ++i) {
                float upd = c0 * m[i] + ca * r_[i] + cb * s_[i];
                int col = ch * 16 + i;
                upd = (col == p) ? -ca : upd;
                upd = (col == p + 1) ? -cb : upd;
                m[i] = upd;
            }
#pragma unroll
            for (int i = 0; i < 16; ++i) {
                float tv = t_[i] + caT * r_[i] + cbT * s_[i];
                float uv = u_[i] + caU * r_[i] + cbU * s_[i];
                int col = ch * 16 + i;
                tv = (col == p) ? -caT : tv;
                tv = (col == p + 1) ? -cbT : tv;
                uv = (col == p) ? -caU : uv;
                uv = (col == p + 1) ? -cbU : uv;
                t_[i] = tv;
                u_[i] = uv;
            }

            float rpB = tp2 + caT * rT + cbT * sT;
            float rp3B = tp3 + caT * rU + cbT * sU;
            float sp3B = up3 + caU * rU + cbU * sU;
            float grB, gsB;
            if (row == p) {
                grB = -caT; gsB = -caU;
            } else if (row == p + 1) {
                grB = -cbT; gsB = -cbU;
            } else {
                grB = tr + caT * gr + cbT * gs;
                gsB = ur + caU * gr + cbU * gs;
            }
            float i1B = 1.f / rpB;
            float alB = rp3B * i1B;
            float i2B = 1.f / (sp3B - alB * rp3B);
            float c0B, cc, cd;
            if (row == p + 2) {
                c0B = 0.f; cc = i1B + alB * alB * i2B; cd = -alB * i2B;
            } else if (row == p + 3) {
                c0B = 0.f; cc = -alB * i2B; cd = i2B;
            } else {
                float b2B = (gsB - alB * grB) * i2B;
                c0B = 1.f; cc = alB * b2B - grB * i1B; cd = -b2B;
            }
#pragma unroll
            for (int i = 0; i < 16; ++i) {
                float upd = c0B * m[i] + cc * t_[i] + cd * u_[i];
                int col = ch * 16 + i;
                upd = (col == p + 2) ? -cc : upd;
                upd = (col == p + 3) ? -cd : upd;
                m[i] = upd;
            }

            if (pp < 15) {
                if (row >= p + 4 && row < p + 8) {
                    float* dst = Rq + ((pp + 1) & 1) * 256 + (row - (p + 4)) * 64;
#pragma unroll
                    for (int i = 0; i < 4; ++i)
                        ((float4*)dst)[ch * 4 + i] =
                            make_float4(m[i * 4], m[i * 4 + 1], m[i * 4 + 2], m[i * 4 + 3]);
                }
            }
            __syncthreads();
        }

        // ---- paired Sherman-Morrison scan (H = -M) ----
#pragma unroll
        for (int tp = 0; tp < 16; ++tp) {
            const int ta = 2 * tp, tb2 = 2 * tp + 1;
            const int par = tp & 1;
            float pu = 0.f, pw = 0.f, pza = 0.f, pzb = 0.f;
#pragma unroll
            for (int i = 0; i < 4; ++i) {
                float4 xa = ((const float4*)(Xs + ta * 64))[ch * 4 + i];
                float4 xb = ((const float4*)(Xs + tb2 * 64))[ch * 4 + i];
                float4 qa = ((const float4*)(Qs + ta * 64))[ch * 4 + i];
                float4 q4 = ((const float4*)(Qs + tb2 * 64))[ch * 4 + i];
                pu += m[i * 4] * xa.x + m[i * 4 + 1] * xa.y + m[i * 4 + 2] * xa.z + m[i * 4 + 3] * xa.w;
                pw += m[i * 4] * xb.x + m[i * 4 + 1] * xb.y + m[i * 4 + 2] * xb.z + m[i * 4 + 3] * xb.w;
                pza += m[i * 4] * qa.x + m[i * 4 + 1] * qa.y + m[i * 4 + 2] * qa.z + m[i * 4 + 3] * qa.w;
                pzb += m[i * 4] * q4.x + m[i * 4 + 1] * q4.y + m[i * 4 + 2] * q4.z + m[i * 4 + 3] * q4.w;
            }
            pu += __shfl_xor(pu, 1); pu += __shfl_xor(pu, 2);
            pw += __shfl_xor(pw, 1); pw += __shfl_xor(pw, 2);
            pza += __shfl_xor(pza, 1); pza += __shfl_xor(pza, 2);
            pzb += __shfl_xor(pzb, 1); pzb += __shfl_xor(pzb, 2);
            float u = -pu, w = -pw, za = -pza, zb = -pzb;
            float* rbufP = Rq + par * 256;
            float* sbufP = Rq + par * 256 + 64;
            if (ch == 0) rbufP[row] = u;
            if (ch == 1) sbufP[row] = w;
            float a_ = Xs[ta * 64 + row], b_ = Xs[tb2 * 64 + row];
            float qa_ = Qs[ta * 64 + row], qb_ = Qs[tb2 * 64 + row];
            float d0 = a_ * u, d1 = b_ * u, d2 = b_ * w;
            float d3 = qa_ * u, d4 = qb_ * u, d5 = qb_ * w;
#pragma unroll
            for (int off = 32; off; off >>= 1) {
                d0 += __shfl_xor(d0, off); d1 += __shfl_xor(d1, off);
                d2 += __shfl_xor(d2, off); d3 += __shfl_xor(d3, off);
                d4 += __shfl_xor(d4, off); d5 += __shfl_xor(d5, off);
            }
            if ((tid & 63) == 0) {
                red[par * 24 + 0 * 4 + wav] = d0; red[par * 24 + 1 * 4 + wav] = d1;
                red[par * 24 + 2 * 4 + wav] = d2; red[par * 24 + 3 * 4 + wav] = d3;
                red[par * 24 + 4 * 4 + wav] = d4; red[par * 24 + 5 * 4 + wav] = d5;
            }
            __syncthreads();
            const float* rp_ = red + par * 24;
            float saa = 0.25f * (rp_[0] + rp_[1] + rp_[2] + rp_[3]);
            float sab = 0.25f * (rp_[4] + rp_[5] + rp_[6] + rp_[7]);
            float sbb = 0.25f * (rp_[8] + rp_[9] + rp_[10] + rp_[11]);
            float c1  = 0.25f * (rp_[12] + rp_[13] + rp_[14] + rp_[15]);
            float c2  = 0.25f * (rp_[16] + rp_[17] + rp_[18] + rp_[19]);
            float c3  = 0.25f * (rp_[20] + rp_[21] + rp_[22] + rp_[23]);
            float k1 = 1.f / (1.f + saa);
            float al2 = sab * k1;
            float k2 = 1.f / (1.f + sbb - sab * al2);
            float vr = w - al2 * u;
            if (ch == 0) Po[ta * 64 + row] = za - (c1 * k1) * u;
            if (ch == 1) Po[tb2 * 64 + row] = zb - (c2 * k1) * u - (k2 * (c3 - al2 * c2)) * vr;
            float cu = k1 * u - al2 * k2 * vr;
            float cw = k2 * vr;
#pragma unroll
            for (int i = 0; i < 4; ++i) {
                float4 uj = ((const float4*)rbufP)[ch * 4 + i];
                float4 wj = ((const float4*)sbufP)[ch * 4 + i];
                m[i * 4 + 0] += cu * uj.x + cw * wj.x;
                m[i * 4 + 1] += cu * uj.y + cw * wj.y;
                m[i * 4 + 2] += cu * uj.z + cw * wj.z;
                m[i * 4 + 3] += cu * uj.w + cw * wj.w;
            }
        }
        __syncthreads();

        float4* po4 = (float4*)(preds + ((size_t)chain * T_SEQ + chunk * CS) * DH);
        po4[tid] = ((const float4*)Po)[tid];
        po4[256 + tid] = ((const float4*)Po)[256 + tid];
    } else {
        // ---- kv_gram: D_ck = V_ck^T K_ck ----
        int kb = bid - nInv;
        int chain = kb >> 4, ck = kb & 15;
        float* Vs = smem;
        float* Ks2 = smem + 4096;
        const float4* Vb = (const float4*)(v + ((size_t)chain * T_SEQ + ck * 64) * DH);
        const float4* Kb = (const float4*)(Kv + ((size_t)chain * T_SEQ + ck * 64) * DH);
#pragma unroll
        for (int i = 0; i < 4; ++i) {
            ((float4*)Vs)[i * 256 + tid] = Vb[i * 256 + tid];
            ((float4*)Ks2)[i * 256 + tid] = Kb[i * 256 + tid];
        }
        __syncthreads();

        int tx = tid & 15, ty = tid >> 4;
        float acc[4][4];
#pragma unroll
        for (int i = 0; i < 4; ++i)
#pragma unroll
            for (int j = 0; j < 4; ++j) acc[i][j] = 0.f;

#pragma unroll 4
        for (int t = 0; t < 64; ++t) {
            float a_[4], b_[4];
#pragma unroll
            for (int i = 0; i < 4; ++i) a_[i] = Vs[t * 64 + ty * 4 + i];
#pragma unroll
            for (int j = 0; j < 4; ++j) b_[j] = Ks2[t * 64 + tx * 4 + j];
#pragma unroll
            for (int i = 0; i < 4; ++i)
#pragma unroll
                for (int j = 0; j < 4; ++j) acc[i][j] += a_[i] * b_[j];
        }

        float* dp = D + ((size_t)chain * ACH + ck) * 4096;
#pragma unroll
        for (int i = 0; i < 4; ++i)
            *(float4*)(dp + (ty * 4 + i) * 64 + tx * 4) =
                make_float4(acc[i][0], acc[i][1], acc[i][2], acc[i][3]);
    }
}

// ---------------------------------------------------------------------------
// attn_wot: blocks <256 -> attention chunk; C prefix computed ON THE FLY by
// summing per-chunk D tiles j<ck (same fp32 order as the removed kv_prefix).
// blocks >=256 -> Wo transpose+split.
// ---------------------------------------------------------------------------
__global__ __launch_bounds__(256) void attn_wot(
    const float* __restrict__ P, const float* __restrict__ V,
    const float* __restrict__ Kv, const float* __restrict__ D,
    ushort* __restrict__ A2_hi, ushort* __restrict__ A2_lo,
    const float* __restrict__ Wo,
    ushort* __restrict__ Wot_hi, ushort* __restrict__ Wot_lo) {
    __shared__ float4 smem4[3072];   // 48KB union
    int bid = blockIdx.x;
    int tid = threadIdx.x;

    if (bid < 256) {
        int ck = bid & 15, bh = bid >> 4;
        int tx = tid & 15, ty = tid >> 4;
        float4* Ps = smem4;
        float4* Bs = smem4 + 1024;
        float4* Ks = smem4 + 2048;

        int lr = tid >> 2, lc = tid & 3;
        const float4* Pb = (const float4*)(P + ((size_t)bh * T_SEQ + ck * 64) * DH);
        const float4* Vb = (const float4*)(V + ((size_t)bh * T_SEQ + ck * 64) * DH);
        const float4* Kb = (const float4*)(Kv + ((size_t)bh * T_SEQ + ck * 64) * DH);
        const float4* Db = (const float4*)(D + (size_t)bh * ACH * 4096);

        // C = sum_{j<ck} D_j (exclusive prefix, ascending order)
        float4 cs[4];
        cs[0] = cs[1] = cs[2] = cs[3] = make_float4(0.f, 0.f, 0.f, 0.f);
        for (int j = 0; j < ck; ++j) {
            const float4* Dj = Db + (size_t)j * 1024;
#pragma unroll
            for (int i = 0; i < 4; ++i) {
                float4 t = Dj[lr * 16 + lc + i * 4];
                cs[i].x += t.x; cs[i].y += t.y; cs[i].z += t.z; cs[i].w += t.w;
            }
        }
#pragma unroll
        for (int i = 0; i < 4; ++i) {
            Ps[swz4(lr, lc + i * 4)] = Pb[lr * 16 + lc + i * 4];
            Bs[swz4(lr, lc + i * 4)] = cs[i];
            Ks[swz4(lr, lc + i * 4)] = Kb[lr * 16 + lc + i * 4];
        }

        float4 o[4];
        o[0] = o[1] = o[2] = o[3] = make_float4(0.f, 0.f, 0.f, 0.f);
        __syncthreads();

        const float* Pf = (const float*)Ps;
#pragma unroll 4
        for (int j = 0; j < 64; ++j) {
            float4 b4 = Bs[swz4(j, tx)];
#pragma unroll
            for (int i = 0; i < 4; ++i) {
                float s = Pf[swz4(ty * 4 + i, j >> 2) * 4 + (j & 3)];
                fma4(o[i], s, b4);
            }
        }
        __syncthreads();

#pragma unroll
        for (int i = 0; i < 4; ++i)
            Bs[swz4(lr, lc + i * 4)] = Vb[lr * 16 + lc + i * 4];
        __syncthreads();

        float4 sa[4][4];
#pragma unroll
        for (int i = 0; i < 4; ++i)
#pragma unroll
            for (int j = 0; j < 4; ++j) sa[i][j] = make_float4(0.f, 0.f, 0.f, 0.f);
#pragma unroll
        for (int d4 = 0; d4 < 16; ++d4) {
            float4 a[4], b[4];
#pragma unroll
            for (int i = 0; i < 4; ++i) a[i] = Ps[swz4(ty * 4 + i, d4)];
#pragma unroll
            for (int j = 0; j < 4; ++j) b[j] = Bs[swz4(tx * 4 + j, d4)];
#pragma unroll
            for (int i = 0; i < 4; ++i)
#pragma unroll
                for (int j = 0; j < 4; ++j) {
                    sa[i][j].x += a[i].x * b[j].x;
                    sa[i][j].y += a[i].y * b[j].y;
                    sa[i][j].z += a[i].z * b[j].z;
                    sa[i][j].w += a[i].w * b[j].w;
                }
        }
        __syncthreads();

#pragma unroll
        for (int i = 0; i < 4; ++i) {
            int m = ty * 4 + i;
            float sv[4];
#pragma unroll
            for (int j = 0; j < 4; ++j) {
                float s = sa[i][j].x + sa[i][j].y + sa[i][j].z + sa[i][j].w;
                if ((tx * 4 + j) > m) s = 0.f;
                sv[j] = s;
            }
            Bs[swz4(m, tx)] = make_float4(sv[0], sv[1], sv[2], sv[3]);
        }
        __syncthreads();

        const float* Sf = (const float*)Bs;
#pragma unroll 4
        for (int j = 0; j < 64; ++j) {
            float4 b4 = Ks[swz4(j, tx)];
#pragma unroll
            for (int i = 0; i < 4; ++i) {
                float s = Sf[swz4(ty * 4 + i, j >> 2) * 4 + (j & 3)];
                fma4(o[i], s, b4);
            }
        }

        int kkb = ((bh & 7) << 6) + tx * 4;
#pragma unroll
        for (int i = 0; i < 4; ++i) {
            int t = ck * 64 + ty * 4 + i;
            size_t mrow = (size_t)((bh >> 3) << 10) + t;
            ushort4 h, l;
            split2(o[i].x, h.x, l.x);
            split2(o[i].y, h.y, l.y);
            split2(o[i].z, h.z, l.z);
            split2(o[i].w, h.w, l.w);
            *(ushort4*)&A2_hi[mrow * 512 + kkb] = h;
            *(ushort4*)&A2_lo[mrow * 512 + kkb] = l;
        }
    } else {
        float* Tf = (float*)smem4;       // [64][65]
        int wb = bid - 256;              // 0..63
        int kk0 = (wb >> 3) * 64, n0 = (wb & 7) * 64;
#pragma unroll
        for (int i = 0; i < 4; ++i) {
            int rl = i * 16 + (tid >> 4);
            int rs = rl * 8 + (kk0 >> 6);   // (d,H) interleave remap
            float4 vv = *(const float4*)&Wo[(size_t)rs * 512 + n0 + (tid & 15) * 4];
            Tf[rl * 65 + (tid & 15) * 4 + 0] = vv.x;
            Tf[rl * 65 + (tid & 15) * 4 + 1] = vv.y;
            Tf[rl * 65 + (tid & 15) * 4 + 2] = vv.z;
            Tf[rl * 65 + (tid & 15) * 4 + 3] = vv.w;
        }
        __syncthreads();
        int nl = tid >> 2, kl = (tid & 3) * 16;
#pragma unroll
        for (int j4 = 0; j4 < 4; ++j4) {
            ushort4 h4, l4;
            split2(Tf[(kl + j4 * 4 + 0) * 65 + nl], h4.x, l4.x);
            split2(Tf[(kl + j4 * 4 + 1) * 65 + nl], h4.y, l4.y);
            split2(Tf[(kl + j4 * 4 + 2) * 65 + nl], h4.z, l4.z);
            split2(Tf[(kl + j4 * 4 + 3) * 65 + nl], h4.w, l4.w);
            size_t dst = (size_t)(n0 + nl) * 512 + kk0 + kl + j4 * 4;
            *(ushort4*)&Wot_hi[dst] = h4;
            *(ushort4*)&Wot_lo[dst] = l4;
        }
    }
}

extern "C" void kernel_launch(void* const* d_in, const int* in_sizes, int n_in,
                              void* d_out, int out_size, void* d_ws, size_t ws_size,
                              hipStream_t stream) {
    const float* x = (const float*)d_in[0];
    const float* Wq = (const float*)d_in[1];
    const float* Wk = (const float*)d_in[2];
    const float* Wv = (const float*)d_in[3];
    const float* Wo = (const float*)d_in[4];
    const float* lambdas = (const float*)d_in[5];
    float* out = (float*)d_out;

    float* ws = (float*)d_ws;
    const size_t SZ = (size_t)NB * NH * T_SEQ * DH;  // 1048576 floats (4 MB)
    float* q = ws;                 // [0,1M); Wot lives here after invscan
    float* k = ws + SZ;            // [1M,2M)
    float* v = ws + 2 * SZ;        // [2M,3M)
    float* preds = ws + 3 * SZ;    // slotD: x hi/lo -> preds
    ushort* x_hi = (ushort*)(ws + 3 * SZ);
    ushort* x_lo = (ushort*)(ws + 3 * SZ + SZ / 2);
    float* g = ws + 4 * SZ;        // [4M,6M): Wt -> g
    ushort* Wt_hi = (ushort*)(ws + 4 * SZ);
    ushort* Wt_lo = (ushort*)(ws + 4 * SZ + 393216);
    ushort* A2_hi = (ushort*)(ws + 5 * SZ);            // [5M,6M) after invscan
    ushort* A2_lo = (ushort*)(ws + 5 * SZ + SZ / 2);
    ushort* Wot_hi = (ushort*)ws;                      // q region (dead)
    ushort* Wot_lo = (ushort*)(ws + 131072);

    bool big = ws_size >= (size_t)7 * SZ * sizeof(float);
    float* dbuf = big ? (ws + 6 * SZ) : g;

    prep_qkv<<<dim3(8, 8, 4), 256, 0, stream>>>(x, Wq, Wk, Wv,
                                                x_hi, x_lo, Wt_hi, Wt_lo);
    mfma_gemm<0><<<dim3(16, 8, 3), 256, 0, stream>>>(
        x_hi, x_lo, Wt_hi, Wt_lo, q, k, v);
    gram_kernel<<<dim3(NCHAIN, NCH), 256, 0, stream>>>(v, g);
    prefix_kernel<<<dim3(256), 256, 0, stream>>>(g);
    if (big) {
        invscan_kv<<<dim3(NCHAIN * NCH + NCHAIN * ACH), 256, 0, stream>>>(
            NCHAIN * NCH, g, v, q, lambdas, preds, k, dbuf);
    } else {
        invscan_kv<<<dim3(NCHAIN * NCH), 256, 0, stream>>>(
            NCHAIN * NCH, g, v, q, lambdas, preds, k, dbuf);
        invscan_kv<<<dim3(NCHAIN * ACH), 256, 0, stream>>>(
            0, g, v, q, lambdas, preds, k, dbuf);
    }
    attn_wot<<<dim3(320), 256, 0, stream>>>(preds, v, k, dbuf, A2_hi, A2_lo,
                                            Wo, Wot_hi, Wot_lo);
    mfma_gemm<1><<<dim3(16, 8, 1), 256, 0, stream>>>(
        (const ushort*)A2_hi, (const ushort*)A2_lo, Wot_hi, Wot_lo,
        out, out, out);
}

// Round 19
// 118.211 us; speedup vs baseline: 1.0978x; 1.0543x over previous
//
#include <hip/hip_runtime.h>

#define T_SEQ 1024
#define DH 64
#define NH 8
#define NB 2
#define EMB 512
#define CS 32      // tokens per scan chunk
#define NCH 32     // chunks per chain
#define ACH 16     // attention chunks per chain (64 tokens each)
#define NCHAIN 16  // B*H

typedef __attribute__((ext_vector_type(8))) short bf16x8;
typedef __attribute__((ext_vector_type(4))) float f32x4;

__device__ __forceinline__ int swz4(int r, int c4) {
    return r * 16 + ((c4 ^ (r >> 2)) & 15);
}

__device__ __forceinline__ void fma4(float4& o, float s, const float4& b) {
    o.x += s * b.x; o.y += s * b.y; o.z += s * b.z; o.w += s * b.w;
}

__device__ __forceinline__ ushort f2bf(float f) {
    unsigned u = __float_as_uint(f);
    return (ushort)((u + 0x7FFFu + ((u >> 16) & 1u)) >> 16);
}
__device__ __forceinline__ float bf2f(ushort h) {
    return __uint_as_float(((unsigned)h) << 16);
}
__device__ __forceinline__ void split2(float f, ushort& hi, ushort& lo) {
    hi = f2bf(f);
    lo = f2bf(f - bf2f(hi));
}

// ---------------------------------------------------------------------------
// prep_qkv: z<3 -> transpose+split W{q,k,v}; z==3 -> split x.
// ---------------------------------------------------------------------------
__global__ __launch_bounds__(256) void prep_qkv(
    const float* __restrict__ x, const float* __restrict__ W0,
    const float* __restrict__ W1, const float* __restrict__ W2,
    ushort* __restrict__ x_hi, ushort* __restrict__ x_lo,
    ushort* __restrict__ Wt_hi, ushort* __restrict__ Wt_lo) {
    int zz = blockIdx.z;
    int t = threadIdx.x;
    __shared__ float T[64][65];
    if (zz < 3) {
        const float* W = (zz == 0) ? W0 : (zz == 1) ? W1 : W2;
        ushort* hi = Wt_hi + (size_t)zz * 262144;
        ushort* lo = Wt_lo + (size_t)zz * 262144;
        int kk0 = blockIdx.x * 64, n0 = blockIdx.y * 64;
#pragma unroll
        for (int i = 0; i < 4; ++i) {
            int rl = i * 16 + (t >> 4);
            float4 vv = *(const float4*)&W[(size_t)(kk0 + rl) * 512 + n0 + (t & 15) * 4];
            T[rl][(t & 15) * 4 + 0] = vv.x;
            T[rl][(t & 15) * 4 + 1] = vv.y;
            T[rl][(t & 15) * 4 + 2] = vv.z;
            T[rl][(t & 15) * 4 + 3] = vv.w;
        }
        __syncthreads();
        int nl = t >> 2, kl = (t & 3) * 16;
#pragma unroll
        for (int j4 = 0; j4 < 4; ++j4) {
            ushort4 h4, l4;
            split2(T[kl + j4 * 4 + 0][nl], h4.x, l4.x);
            split2(T[kl + j4 * 4 + 1][nl], h4.y, l4.y);
            split2(T[kl + j4 * 4 + 2][nl], h4.z, l4.z);
            split2(T[kl + j4 * 4 + 3][nl], h4.w, l4.w);
            size_t dst = (size_t)(n0 + nl) * 512 + kk0 + kl + j4 * 4;
            *(ushort4*)&hi[dst] = h4;
            *(ushort4*)&lo[dst] = l4;
        }
    } else {
        int bid = blockIdx.y * 8 + blockIdx.x;
        const float4* in = (const float4*)x;
        ushort4* hi = (ushort4*)x_hi;
        ushort4* lo = (ushort4*)x_lo;
#pragma unroll
        for (int i = 0; i < 16; ++i) {
            int id = (bid * 16 + i) * 256 + t;
            float4 xv = in[id];
            ushort4 h, l;
            split2(xv.x, h.x, l.x);
            split2(xv.y, h.y, l.y);
            split2(xv.z, h.z, l.z);
            split2(xv.w, h.w, l.w);
            hi[id] = h;
            lo[id] = l;
        }
    }
}

// ---------------------------------------------------------------------------
// MFMA GEMM: C[2048][512] = A * B, bf16 hi/lo split, Bt[n][k] transposed.
// 64x64 tile, 4 waves (2x2), wave tile 32x32 -> 2x grid for occupancy.
// ---------------------------------------------------------------------------
template <int MODE>
__global__ __launch_bounds__(256) void mfma_gemm(
    const ushort* __restrict__ Ahi, const ushort* __restrict__ Alo,
    const ushort* __restrict__ Bth, const ushort* __restrict__ Btl,
    float* __restrict__ o0, float* __restrict__ o1, float* __restrict__ o2) {
    int bm = blockIdx.x, bn = blockIdx.y, zz = blockIdx.z;
    const ushort* Bh = Bth + (size_t)zz * 262144;
    const ushort* Bl = Btl + (size_t)zz * 262144;
    float* out = (MODE == 0) ? ((zz == 0) ? o0 : (zz == 1) ? o1 : o2) : o0;

    __shared__ ushort Ash[64 * 40];
    __shared__ ushort Asl[64 * 40];
    __shared__ ushort Bsh[64 * 40];
    __shared__ ushort Bsl[64 * 40];

    int tid = threadIdx.x;
    int lane = tid & 63, wid = tid >> 6;
    int wm = wid >> 1, wn = wid & 1;
    int fr = lane & 15, fk = (lane >> 4) * 8;
    int sr = tid >> 2, sc = (tid & 3) * 8;

    f32x4 zero = {0.f, 0.f, 0.f, 0.f};
    f32x4 acc[2][2];
#pragma unroll
    for (int f = 0; f < 2; ++f)
#pragma unroll
        for (int g = 0; g < 2; ++g) acc[f][g] = zero;

    const ushort* gAh = Ahi + (size_t)(bm * 64 + sr) * 512 + sc;
    const ushort* gAl = Alo + (size_t)(bm * 64 + sr) * 512 + sc;
    const ushort* gBh = Bh + (size_t)(bn * 64 + sr) * 512 + sc;
    const ushort* gBl = Bl + (size_t)(bn * 64 + sr) * 512 + sc;

    for (int k0 = 0; k0 < 512; k0 += 32) {
        uint4 a0 = *(const uint4*)(gAh + k0);
        uint4 a2 = *(const uint4*)(gAl + k0);
        uint4 b0 = *(const uint4*)(gBh + k0);
        uint4 b1 = *(const uint4*)(gBl + k0);
        __syncthreads();
        *(uint4*)&Ash[sr * 40 + sc] = a0;
        *(uint4*)&Asl[sr * 40 + sc] = a2;
        *(uint4*)&Bsh[sr * 40 + sc] = b0;
        *(uint4*)&Bsl[sr * 40 + sc] = b1;
        __syncthreads();
        bf16x8 ah[2], al[2], bh[2], blo[2];
#pragma unroll
        for (int f = 0; f < 2; ++f) {
            int r = wm * 32 + f * 16 + fr;
            ah[f] = *(const bf16x8*)&Ash[r * 40 + fk];
            al[f] = *(const bf16x8*)&Asl[r * 40 + fk];
        }
#pragma unroll
        for (int g = 0; g < 2; ++g) {
            int r = wn * 32 + g * 16 + fr;
            bh[g] = *(const bf16x8*)&Bsh[r * 40 + fk];
            blo[g] = *(const bf16x8*)&Bsl[r * 40 + fk];
        }
#pragma unroll
        for (int f = 0; f < 2; ++f)
#pragma unroll
            for (int g = 0; g < 2; ++g) {
                acc[f][g] = __builtin_amdgcn_mfma_f32_16x16x32_bf16(
                    ah[f], bh[g], acc[f][g], 0, 0, 0);
                acc[f][g] = __builtin_amdgcn_mfma_f32_16x16x32_bf16(
                    ah[f], blo[g], acc[f][g], 0, 0, 0);
                acc[f][g] = __builtin_amdgcn_mfma_f32_16x16x32_bf16(
                    al[f], bh[g], acc[f][g], 0, 0, 0);
            }
    }

    int rbase = (lane >> 4) * 4;
#pragma unroll
    for (int f = 0; f < 2; ++f)
#pragma unroll
        for (int g = 0; g < 2; ++g)
#pragma unroll
            for (int j = 0; j < 4; ++j) {
                int m = bm * 64 + wm * 32 + f * 16 + rbase + j;
                int n = bn * 64 + wn * 32 + g * 16 + (lane & 15);
                float val = acc[f][g][j];
                if (MODE == 0) {
                    int b = m >> 10, tt = m & 1023;
                    int h = n >> 6, d = n & 63;
                    out[(((size_t)(b * 8 + h) * 1024 + tt) << 6) + d] = val;
                } else {
                    out[(size_t)m * 512 + n] = val;
                }
            }
}

// ---------------------------------------------------------------------------
// per-chunk Gram G = X^T X (64x64, CS tokens)
// ---------------------------------------------------------------------------
__global__ __launch_bounds__(256) void gram_kernel(
    const float* __restrict__ v, float* __restrict__ g) {
    int chain = blockIdx.x, chunk = blockIdx.y;
    const float* X = v + ((size_t)chain * T_SEQ + chunk * CS) * DH;
    __shared__ float Xs[CS * 64];
    int tid = threadIdx.x;
#pragma unroll
    for (int i = 0; i < (CS * 16) / 256; ++i)
        ((float4*)Xs)[i * 256 + tid] = ((const float4*)X)[i * 256 + tid];
    __syncthreads();

    int tx = tid & 15, ty = tid >> 4;
    float acc[4][4];
#pragma unroll
    for (int i = 0; i < 4; ++i)
#pragma unroll
        for (int j = 0; j < 4; ++j) acc[i][j] = 0.f;

#pragma unroll 4
    for (int t = 0; t < CS; ++t) {
        float a_[4], b_[4];
#pragma unroll
        for (int i = 0; i < 4; ++i) a_[i] = Xs[t * 64 + ty * 4 + i];
#pragma unroll
        for (int j = 0; j < 4; ++j) b_[j] = Xs[t * 64 + tx * 4 + j];
#pragma unroll
        for (int i = 0; i < 4; ++i)
#pragma unroll
            for (int j = 0; j < 4; ++j) acc[i][j] += a_[i] * b_[j];
    }

    float* gp = g + ((size_t)chain * NCH + chunk) * 4096;
#pragma unroll
    for (int i = 0; i < 4; ++i)
        *(float4*)(gp + (ty * 4 + i) * 64 + tx * 4) =
            make_float4(acc[i][0], acc[i][1], acc[i][2], acc[i][3]);
}

// ---------------------------------------------------------------------------
// exclusive prefix over NCH chunks — register-staged
// ---------------------------------------------------------------------------
__global__ __launch_bounds__(256) void prefix_kernel(float* __restrict__ g) {
    int gid = blockIdx.x * 256 + threadIdx.x;
    int chain = gid >> 12, elem = gid & 4095;
    float* p = g + (size_t)chain * NCH * 4096 + elem;
    float vals[NCH];
#pragma unroll
    for (int c = 0; c < NCH; ++c) vals[c] = p[(size_t)c * 4096];
    float run = 0.f;
#pragma unroll
    for (int c = 0; c < NCH; ++c) {
        float t = vals[c];
        vals[c] = run;
        run += t;
    }
#pragma unroll
    for (int c = 0; c < NCH; ++c) p[(size_t)c * 4096] = vals[c];
}

// ---------------------------------------------------------------------------
// invscan_kv: heterogeneous grid. Blocks < nInv: RANK-4 GJ sweep (16 rounds)
// + rank-2 SM scan (16 rounds). Blocks >= nInv: kv_gram. 32KB LDS union.
// ---------------------------------------------------------------------------
__global__ __launch_bounds__(256) void invscan_kv(
    int nInv,
    const float* __restrict__ g, const float* __restrict__ v,
    const float* __restrict__ q, const float* __restrict__ lambdas,
    float* __restrict__ preds,
    const float* __restrict__ Kv, float* __restrict__ D) {
    __shared__ float smem[8192];
    int bid = blockIdx.x;
    int tid = threadIdx.x;

    if (bid < nInv) {
        int chain = bid >> 5, chunk = bid & 31;
        int row = tid >> 2, ch = tid & 3, wav = tid >> 6;
        float lam = lambdas[chain & (NH - 1)];

        float* Xs = smem;                 // 2048
        float* Qs = smem + 2048;          // 2048
        float* Po = smem + 4096;          // 2048
        float* Rq = smem + 6144;          // [2][4][64] = 512
        float* red = smem + 6656;         // [2][6][4] = 48

        float m[16];
        {
            const float4* gp = (const float4*)(g + ((size_t)chain * NCH + chunk) * 4096);
#pragma unroll
            for (int i = 0; i < 4; ++i) {
                float4 t4 = gp[row * 16 + ch * 4 + i];
                m[i * 4 + 0] = t4.x; m[i * 4 + 1] = t4.y;
                m[i * 4 + 2] = t4.z; m[i * 4 + 3] = t4.w;
            }
        }
#pragma unroll
        for (int i = 0; i < 16; ++i)
            if (ch * 16 + i == row) m[i] += lam;

        const float4* vb = (const float4*)(v + ((size_t)chain * T_SEQ + chunk * CS) * DH);
        const float4* qb = (const float4*)(q + ((size_t)chain * T_SEQ + chunk * CS) * DH);
        ((float4*)Xs)[tid] = vb[tid];
        ((float4*)Xs)[256 + tid] = vb[256 + tid];
        ((float4*)Qs)[tid] = qb[tid];
        ((float4*)Qs)[256 + tid] = qb[256 + tid];

        if (row < 4) {
#pragma unroll
            for (int i = 0; i < 4; ++i)
                ((float4*)(Rq + row * 64))[ch * 4 + i] =
                    make_float4(m[i * 4], m[i * 4 + 1], m[i * 4 + 2], m[i * 4 + 3]);
        }
        __syncthreads();

        // ---- RANK-4 GJ sweep: pivots (p..p+3), 16 rounds ----
#pragma unroll
        for (int pp = 0; pp < 16; ++pp) {
            const int p = 4 * pp;
            const float* rb = Rq + (pp & 1) * 256;
            const float* sb = rb + 64;
            const float* tb = rb + 128;
            const float* ub = rb + 192;
            float r_[16], s_[16], t_[16], u_[16];
#pragma unroll
            for (int i = 0; i < 4; ++i) {
                float4 a4 = ((const float4*)rb)[ch * 4 + i];
                r_[i * 4] = a4.x; r_[i * 4 + 1] = a4.y; r_[i * 4 + 2] = a4.z; r_[i * 4 + 3] = a4.w;
                float4 b4 = ((const float4*)sb)[ch * 4 + i];
                s_[i * 4] = b4.x; s_[i * 4 + 1] = b4.y; s_[i * 4 + 2] = b4.z; s_[i * 4 + 3] = b4.w;
                float4 c4 = ((const float4*)tb)[ch * 4 + i];
                t_[i * 4] = c4.x; t_[i * 4 + 1] = c4.y; t_[i * 4 + 2] = c4.z; t_[i * 4 + 3] = c4.w;
                float4 d4 = ((const float4*)ub)[ch * 4 + i];
                u_[i * 4] = d4.x; u_[i * 4 + 1] = d4.y; u_[i * 4 + 2] = d4.z; u_[i * 4 + 3] = d4.w;
            }
            float rp = rb[p], rp1 = rb[p + 1], sp1 = sb[p + 1];
            float rT = rb[p + 2], sT = sb[p + 2];
            float rU = rb[p + 3], sU = sb[p + 3];
            float tp2 = tb[p + 2], tp3 = tb[p + 3], up3 = ub[p + 3];
            float gr = rb[row], gs = sb[row];
            float tr = tb[row], ur = ub[row];

            float i1 = 1.f / rp;
            float al = rp1 * i1;
            float i2 = 1.f / (sp1 - al * rp1);
            float b2T = (sT - al * rT) * i2;
            float caT = al * b2T - rT * i1, cbT = -b2T;
            float b2U = (sU - al * rU) * i2;
            float caU = al * b2U - rU * i1, cbU = -b2U;
            float c0, ca, cb;
            if (row == p) {
                c0 = 0.f; ca = i1 + al * al * i2; cb = -al * i2;
            } else if (row == p + 1) {
                c0 = 0.f; ca = -al * i2; cb = i2;
            } else {
                float b2 = (gs - al * gr) * i2;
                c0 = 1.f; ca = al * b2 - gr * i1; cb = -b2;
            }
#pragma unroll
            for (int i = 0; i < 16; ++i) {
                float upd = c0 * m[i] + ca * r_[i] + cb * s_[i];
                int col = ch * 16 + i;
                upd = (col == p) ? -ca : upd;
                upd = (col == p + 1) ? -cb : upd;
                m[i] = upd;
            }
#pragma unroll
            for (int i = 0; i < 16; ++i) {
                float tv = t_[i] + caT * r_[i] + cbT * s_[i];
                float uv = u_[i] + caU * r_[i] + cbU * s_[i];
                int col = ch * 16 + i;
                tv = (col == p) ? -caT : tv;
                tv = (col == p + 1) ? -cbT : tv;
                uv = (col == p) ? -caU : uv;
                uv = (col == p + 1) ? -cbU : uv;
                t_[i] = tv;
                u_[i] = uv;
            }

            float rpB = tp2 + caT * rT + cbT * sT;
            float rp3B = tp3 + caT * rU + cbT * sU;
            float sp3B = up3 + caU * rU + cbU * sU;
            float grB, gsB;
            if (row == p) {
                grB = -caT; gsB = -caU;
            } else if (row == p + 1) {
                grB = -cbT; gsB = -cbU;
            } else {
                grB = tr + caT * gr + cbT * gs;
                gsB = ur + caU * gr + cbU * gs;
            }
            float i1B = 1.f / rpB;
            float alB = rp3B * i1B;
            float i2B = 1.f / (sp3B - alB * rp3B);
            float c0B, cc, cd;
            if (row == p + 2) {
                c0B = 0.f; cc = i1B + alB * alB * i2B; cd = -alB * i2B;
            } else if (row == p + 3) {
                c0B = 0.f; cc = -alB * i2B; cd = i2B;
            } else {
                float b2B = (gsB - alB * grB) * i2B;
                c0B = 1.f; cc = alB * b2B - grB * i1B; cd = -b2B;
            }
#pragma unroll
            for (int i = 0; i < 16; ++i) {
                float upd = c0B * m[i] + cc * t_[i] + cd * u_[i];
                int col = ch * 16 + i;
                upd = (col == p + 2) ? -cc : upd;
                upd = (col == p + 3) ? -cd : upd;
                m[i] = upd;
            }

            if (pp < 15) {
                if (row >= p + 4 && row < p + 8) {
                    float* dst = Rq + ((pp + 1) & 1) * 256 + (row - (p + 4)) * 64;
#pragma unroll
                    for (int i = 0; i < 4; ++i)
                        ((float4*)dst)[ch * 4 + i] =
                            make_float4(m[i * 4], m[i * 4 + 1], m[i * 4 + 2], m[i * 4 + 3]);
                }
            }
            __syncthreads();
        }

        // ---- paired Sherman-Morrison scan (H = -M) ----
#pragma unroll
        for (int tp = 0; tp < 16; ++tp) {
            const int ta = 2 * tp, tb2 = 2 * tp + 1;
            const int par = tp & 1;
            float pu = 0.f, pw = 0.f, pza = 0.f, pzb = 0.f;
#pragma unroll
            for (int i = 0; i < 4; ++i) {
                float4 xa = ((const float4*)(Xs + ta * 64))[ch * 4 + i];
                float4 xb = ((const float4*)(Xs + tb2 * 64))[ch * 4 + i];
                float4 qa = ((const float4*)(Qs + ta * 64))[ch * 4 + i];
                float4 q4 = ((const float4*)(Qs + tb2 * 64))[ch * 4 + i];
                pu += m[i * 4] * xa.x + m[i * 4 + 1] * xa.y + m[i * 4 + 2] * xa.z + m[i * 4 + 3] * xa.w;
                pw += m[i * 4] * xb.x + m[i * 4 + 1] * xb.y + m[i * 4 + 2] * xb.z + m[i * 4 + 3] * xb.w;
                pza += m[i * 4] * qa.x + m[i * 4 + 1] * qa.y + m[i * 4 + 2] * qa.z + m[i * 4 + 3] * qa.w;
                pzb += m[i * 4] * q4.x + m[i * 4 + 1] * q4.y + m[i * 4 + 2] * q4.z + m[i * 4 + 3] * q4.w;
            }
            pu += __shfl_xor(pu, 1); pu += __shfl_xor(pu, 2);
            pw += __shfl_xor(pw, 1); pw += __shfl_xor(pw, 2);
            pza += __shfl_xor(pza, 1); pza += __shfl_xor(pza, 2);
            pzb += __shfl_xor(pzb, 1); pzb += __shfl_xor(pzb, 2);
            float u = -pu, w = -pw, za = -pza, zb = -pzb;
            float* rbufP = Rq + par * 256;
            float* sbufP = Rq + par * 256 + 64;
            if (ch == 0) rbufP[row] = u;
            if (ch == 1) sbufP[row] = w;
            float a_ = Xs[ta * 64 + row], b_ = Xs[tb2 * 64 + row];
            float qa_ = Qs[ta * 64 + row], qb_ = Qs[tb2 * 64 + row];
            float d0 = a_ * u, d1 = b_ * u, d2 = b_ * w;
            float d3 = qa_ * u, d4 = qb_ * u, d5 = qb_ * w;
#pragma unroll
            for (int off = 32; off; off >>= 1) {
                d0 += __shfl_xor(d0, off); d1 += __shfl_xor(d1, off);
                d2 += __shfl_xor(d2, off); d3 += __shfl_xor(d3, off);
                d4 += __shfl_xor(d4, off); d5 += __shfl_xor(d5, off);
            }
            if ((tid & 63) == 0) {
                red[par * 24 + 0 * 4 + wav] = d0; red[par * 24 + 1 * 4 + wav] = d1;
                red[par * 24 + 2 * 4 + wav] = d2; red[par * 24 + 3 * 4 + wav] = d3;
                red[par * 24 + 4 * 4 + wav] = d4; red[par * 24 + 5 * 4 + wav] = d5;
            }
            __syncthreads();
            const float* rp_ = red + par * 24;
            float saa = 0.25f * (rp_[0] + rp_[1] + rp_[2] + rp_[3]);
            float sab = 0.25f * (rp_[4] + rp_[5] + rp_[6] + rp_[7]);
            float sbb = 0.25f * (rp_[8] + rp_[9] + rp_[10] + rp_[11]);
            float c1  = 0.25f * (rp_[12] + rp_[13] + rp_[14] + rp_[15]);
            float c2  = 0.25f * (rp_[16] + rp_[17] + rp_[18] + rp_[19]);
            float c3  = 0.25f * (rp_[20] + rp_[21] + rp_[22] + rp_[23]);
            float k1 = 1.f / (1.f + saa);
            float al2 = sab * k1;
            float k2 = 1.f / (1.f + sbb - sab * al2);
            float vr = w - al2 * u;
            if (ch == 0) Po[ta * 64 + row] = za - (c1 * k1) * u;
            if (ch == 1) Po[tb2 * 64 + row] = zb - (c2 * k1) * u - (k2 * (c3 - al2 * c2)) * vr;
            float cu = k1 * u - al2 * k2 * vr;
            float cw = k2 * vr;
#pragma unroll
            for (int i = 0; i < 4; ++i) {
                float4 uj = ((const float4*)rbufP)[ch * 4 + i];
                float4 wj = ((const float4*)sbufP)[ch * 4 + i];
                m[i * 4 + 0] += cu * uj.x + cw * wj.x;
                m[i * 4 + 1] += cu * uj.y + cw * wj.y;
                m[i * 4 + 2] += cu * uj.z + cw * wj.z;
                m[i * 4 + 3] += cu * uj.w + cw * wj.w;
            }
        }
        __syncthreads();

        float4* po4 = (float4*)(preds + ((size_t)chain * T_SEQ + chunk * CS) * DH);
        po4[tid] = ((const float4*)Po)[tid];
        po4[256 + tid] = ((const float4*)Po)[256 + tid];
    } else {
        // ---- kv_gram: D_ck = V_ck^T K_ck ----
        int kb = bid - nInv;
        int chain = kb >> 4, ck = kb & 15;
        float* Vs = smem;
        float* Ks2 = smem + 4096;
        const float4* Vb = (const float4*)(v + ((size_t)chain * T_SEQ + ck * 64) * DH);
        const float4* Kb = (const float4*)(Kv + ((size_t)chain * T_SEQ + ck * 64) * DH);
#pragma unroll
        for (int i = 0; i < 4; ++i) {
            ((float4*)Vs)[i * 256 + tid] = Vb[i * 256 + tid];
            ((float4*)Ks2)[i * 256 + tid] = Kb[i * 256 + tid];
        }
        __syncthreads();

        int tx = tid & 15, ty = tid >> 4;
        float acc[4][4];
#pragma unroll
        for (int i = 0; i < 4; ++i)
#pragma unroll
            for (int j = 0; j < 4; ++j) acc[i][j] = 0.f;

#pragma unroll 4
        for (int t = 0; t < 64; ++t) {
            float a_[4], b_[4];
#pragma unroll
            for (int i = 0; i < 4; ++i) a_[i] = Vs[t * 64 + ty * 4 + i];
#pragma unroll
            for (int j = 0; j < 4; ++j) b_[j] = Ks2[t * 64 + tx * 4 + j];
#pragma unroll
            for (int i = 0; i < 4; ++i)
#pragma unroll
                for (int j = 0; j < 4; ++j) acc[i][j] += a_[i] * b_[j];
        }

        float* dp = D + ((size_t)chain * ACH + ck) * 4096;
#pragma unroll
        for (int i = 0; i < 4; ++i)
            *(float4*)(dp + (ty * 4 + i) * 64 + tx * 4) =
                make_float4(acc[i][0], acc[i][1], acc[i][2], acc[i][3]);
    }
}

// ---------------------------------------------------------------------------
// attn_wot: blocks <256 -> attention chunk; C prefix computed ON THE FLY by
// summing per-chunk D tiles j<ck. blocks >=256 -> Wo transpose+split.
// ---------------------------------------------------------------------------
__global__ __launch_bounds__(256) void attn_wot(
    const float* __restrict__ P, const float* __restrict__ V,
    const float* __restrict__ Kv, const float* __restrict__ D,
    ushort* __restrict__ A2_hi, ushort* __restrict__ A2_lo,
    const float* __restrict__ Wo,
    ushort* __restrict__ Wot_hi, ushort* __restrict__ Wot_lo) {
    __shared__ float4 smem4[3072];   // 48KB union
    int bid = blockIdx.x;
    int tid = threadIdx.x;

    if (bid < 256) {
        int ck = bid & 15, bh = bid >> 4;
        int tx = tid & 15, ty = tid >> 4;
        float4* Ps = smem4;
        float4* Bs = smem4 + 1024;
        float4* Ks = smem4 + 2048;

        int lr = tid >> 2, lc = tid & 3;
        const float4* Pb = (const float4*)(P + ((size_t)bh * T_SEQ + ck * 64) * DH);
        const float4* Vb = (const float4*)(V + ((size_t)bh * T_SEQ + ck * 64) * DH);
        const float4* Kb = (const float4*)(Kv + ((size_t)bh * T_SEQ + ck * 64) * DH);
        const float4* Db = (const float4*)(D + (size_t)bh * ACH * 4096);

        float4 cs[4];
        cs[0] = cs[1] = cs[2] = cs[3] = make_float4(0.f, 0.f, 0.f, 0.f);
        for (int j = 0; j < ck; ++j) {
            const float4* Dj = Db + (size_t)j * 1024;
#pragma unroll
            for (int i = 0; i < 4; ++i) {
                float4 t = Dj[lr * 16 + lc + i * 4];
                cs[i].x += t.x; cs[i].y += t.y; cs[i].z += t.z; cs[i].w += t.w;
            }
        }
#pragma unroll
        for (int i = 0; i < 4; ++i) {
            Ps[swz4(lr, lc + i * 4)] = Pb[lr * 16 + lc + i * 4];
            Bs[swz4(lr, lc + i * 4)] = cs[i];
            Ks[swz4(lr, lc + i * 4)] = Kb[lr * 16 + lc + i * 4];
        }

        float4 o[4];
        o[0] = o[1] = o[2] = o[3] = make_float4(0.f, 0.f, 0.f, 0.f);
        __syncthreads();

        const float* Pf = (const float*)Ps;
#pragma unroll 4
        for (int j = 0; j < 64; ++j) {
            float4 b4 = Bs[swz4(j, tx)];
#pragma unroll
            for (int i = 0; i < 4; ++i) {
                float s = Pf[swz4(ty * 4 + i, j >> 2) * 4 + (j & 3)];
                fma4(o[i], s, b4);
            }
        }
        __syncthreads();

#pragma unroll
        for (int i = 0; i < 4; ++i)
            Bs[swz4(lr, lc + i * 4)] = Vb[lr * 16 + lc + i * 4];
        __syncthreads();

        float4 sa[4][4];
#pragma unroll
        for (int i = 0; i < 4; ++i)
#pragma unroll
            for (int j = 0; j < 4; ++j) sa[i][j] = make_float4(0.f, 0.f, 0.f, 0.f);
#pragma unroll
        for (int d4 = 0; d4 < 16; ++d4) {
            float4 a[4], b[4];
#pragma unroll
            for (int i = 0; i < 4; ++i) a[i] = Ps[swz4(ty * 4 + i, d4)];
#pragma unroll
            for (int j = 0; j < 4; ++j) b[j] = Bs[swz4(tx * 4 + j, d4)];
#pragma unroll
            for (int i = 0; i < 4; ++i)
#pragma unroll
                for (int j = 0; j < 4; ++j) {
                    sa[i][j].x += a[i].x * b[j].x;
                    sa[i][j].y += a[i].y * b[j].y;
                    sa[i][j].z += a[i].z * b[j].z;
                    sa[i][j].w += a[i].w * b[j].w;
                }
        }
        __syncthreads();

#pragma unroll
        for (int i = 0; i < 4; ++i) {
            int m = ty * 4 + i;
            float sv[4];
#pragma unroll
            for (int j = 0; j < 4; ++j) {
                float s = sa[i][j].x + sa[i][j].y + sa[i][j].z + sa[i][j].w;
                if ((tx * 4 + j) > m) s = 0.f;
                sv[j] = s;
            }
            Bs[swz4(m, tx)] = make_float4(sv[0], sv[1], sv[2], sv[3]);
        }
        __syncthreads();

        const float* Sf = (const float*)Bs;
#pragma unroll 4
        for (int j = 0; j < 64; ++j) {
            float4 b4 = Ks[swz4(j, tx)];
#pragma unroll
            for (int i = 0; i < 4; ++i) {
                float s = Sf[swz4(ty * 4 + i, j >> 2) * 4 + (j & 3)];
                fma4(o[i], s, b4);
            }
        }

        int kkb = ((bh & 7) << 6) + tx * 4;
#pragma unroll
        for (int i = 0; i < 4; ++i) {
            int t = ck * 64 + ty * 4 + i;
            size_t mrow = (size_t)((bh >> 3) << 10) + t;
            ushort4 h, l;
            split2(o[i].x, h.x, l.x);
            split2(o[i].y, h.y, l.y);
            split2(o[i].z, h.z, l.z);
            split2(o[i].w, h.w, l.w);
            *(ushort4*)&A2_hi[mrow * 512 + kkb] = h;
            *(ushort4*)&A2_lo[mrow * 512 + kkb] = l;
        }
    } else {
        float* Tf = (float*)smem4;       // [64][65]
        int wb = bid - 256;              // 0..63
        int kk0 = (wb >> 3) * 64, n0 = (wb & 7) * 64;
#pragma unroll
        for (int i = 0; i < 4; ++i) {
            int rl = i * 16 + (tid >> 4);
            int rs = rl * 8 + (kk0 >> 6);   // (d,H) interleave remap
            float4 vv = *(const float4*)&Wo[(size_t)rs * 512 + n0 + (tid & 15) * 4];
            Tf[rl * 65 + (tid & 15) * 4 + 0] = vv.x;
            Tf[rl * 65 + (tid & 15) * 4 + 1] = vv.y;
            Tf[rl * 65 + (tid & 15) * 4 + 2] = vv.z;
            Tf[rl * 65 + (tid & 15) * 4 + 3] = vv.w;
        }
        __syncthreads();
        int nl = tid >> 2, kl = (tid & 3) * 16;
#pragma unroll
        for (int j4 = 0; j4 < 4; ++j4) {
            ushort4 h4, l4;
            split2(Tf[(kl + j4 * 4 + 0) * 65 + nl], h4.x, l4.x);
            split2(Tf[(kl + j4 * 4 + 1) * 65 + nl], h4.y, l4.y);
            split2(Tf[(kl + j4 * 4 + 2) * 65 + nl], h4.z, l4.z);
            split2(Tf[(kl + j4 * 4 + 3) * 65 + nl], h4.w, l4.w);
            size_t dst = (size_t)(n0 + nl) * 512 + kk0 + kl + j4 * 4;
            *(ushort4*)&Wot_hi[dst] = h4;
            *(ushort4*)&Wot_lo[dst] = l4;
        }
    }
}

extern "C" void kernel_launch(void* const* d_in, const int* in_sizes, int n_in,
                              void* d_out, int out_size, void* d_ws, size_t ws_size,
                              hipStream_t stream) {
    const float* x = (const float*)d_in[0];
    const float* Wq = (const float*)d_in[1];
    const float* Wk = (const float*)d_in[2];
    const float* Wv = (const float*)d_in[3];
    const float* Wo = (const float*)d_in[4];
    const float* lambdas = (const float*)d_in[5];
    float* out = (float*)d_out;

    float* ws = (float*)d_ws;
    const size_t SZ = (size_t)NB * NH * T_SEQ * DH;  // 1048576 floats (4 MB)
    float* q = ws;                 // [0,1M); Wot lives here after invscan
    float* k = ws + SZ;            // [1M,2M)
    float* v = ws + 2 * SZ;        // [2M,3M)
    float* preds = ws + 3 * SZ;    // slotD: x hi/lo -> preds
    ushort* x_hi = (ushort*)(ws + 3 * SZ);
    ushort* x_lo = (ushort*)(ws + 3 * SZ + SZ / 2);
    float* g = ws + 4 * SZ;        // [4M,6M): Wt -> g
    ushort* Wt_hi = (ushort*)(ws + 4 * SZ);
    ushort* Wt_lo = (ushort*)(ws + 4 * SZ + 393216);
    ushort* A2_hi = (ushort*)(ws + 5 * SZ);            // [5M,6M) after invscan
    ushort* A2_lo = (ushort*)(ws + 5 * SZ + SZ / 2);
    ushort* Wot_hi = (ushort*)ws;                      // q region (dead)
    ushort* Wot_lo = (ushort*)(ws + 131072);

    bool big = ws_size >= (size_t)7 * SZ * sizeof(float);
    float* dbuf = big ? (ws + 6 * SZ) : g;

    prep_qkv<<<dim3(8, 8, 4), 256, 0, stream>>>(x, Wq, Wk, Wv,
                                                x_hi, x_lo, Wt_hi, Wt_lo);
    mfma_gemm<0><<<dim3(32, 8, 3), 256, 0, stream>>>(
        x_hi, x_lo, Wt_hi, Wt_lo, q, k, v);
    gram_kernel<<<dim3(NCHAIN, NCH), 256, 0, stream>>>(v, g);
    prefix_kernel<<<dim3(256), 256, 0, stream>>>(g);
    if (big) {
        invscan_kv<<<dim3(NCHAIN * NCH + NCHAIN * ACH), 256, 0, stream>>>(
            NCHAIN * NCH, g, v, q, lambdas, preds, k, dbuf);
    } else {
        invscan_kv<<<dim3(NCHAIN * NCH), 256, 0, stream>>>(
            NCHAIN * NCH, g, v, q, lambdas, preds, k, dbuf);
        invscan_kv<<<dim3(NCHAIN * ACH), 256, 0, stream>>>(
            0, g, v, q, lambdas, preds, k, dbuf);
    }
    attn_wot<<<dim3(320), 256, 0, stream>>>(preds, v, k, dbuf, A2_hi, A2_lo,
                                            Wo, Wot_hi, Wot_lo);
    mfma_gemm<1><<<dim3(32, 8, 1), 256, 0, stream>>>(
        (const ushort*)A2_hi, (const ushort*)A2_lo, Wot_hi, Wot_lo,
        out, out, out);
}